// Round 1
// baseline (1068.944 us; speedup 1.0000x reference)
//
#include <hip/hip_runtime.h>
#include <math.h>

static constexpr int F_IN = 512;
static constexpr int H1V = 180, H1P = 192;
static constexpr int H2V = 120, H2P = 128;
static constexpr int NC  = 40,  NCP = 64;

// ---------------- edge dtype detection (int32 vs int64 layout) -------------
// If edge_index arrived as int64 (little-endian), every odd int32 word is the
// high half of a value < 100000 -> zero. Sample 4096 odd words; any nonzero
// word proves int32 layout. flag: nonzero => int64 mode.
__global__ void k_detect(const int* __restrict__ ei, int* __restrict__ flag) {
    int i = blockIdx.x * 256 + threadIdx.x;   // 4096 threads
    if (ei[2 * i + 1] != 0) flag[0] = 0;      // benign race, all write 0
}

// ---------------- degree histogram + dinv ----------------------------------
__global__ void k_hist(const int* __restrict__ ei, int E, const int* __restrict__ flag,
                       int* __restrict__ deg) {
    int e = blockIdx.x * 256 + threadIdx.x;
    if (e >= E) return;
    int d = flag[0] ? ei[2 * E + 2 * e] : ei[E + e];
    atomicAdd(&deg[d], 1);
}

__global__ void k_dinv(const int* __restrict__ deg, float* __restrict__ dinv, int n) {
    int i = blockIdx.x * 256 + threadIdx.x;
    if (i < n) dinv[i] = rsqrtf((float)(deg[i] + 1));   // +1 self loop
}

// ---------------- exclusive scan (3-kernel) --------------------------------
__global__ void k_scan1(const int* __restrict__ deg, int* __restrict__ rp,
                        int* __restrict__ bsum, int n) {
    __shared__ int s[256];
    int t = threadIdx.x;
    int base = blockIdx.x * 1024 + t * 4;
    int v0 = (base + 0 < n) ? deg[base + 0] : 0;
    int v1 = (base + 1 < n) ? deg[base + 1] : 0;
    int v2 = (base + 2 < n) ? deg[base + 2] : 0;
    int v3 = (base + 3 < n) ? deg[base + 3] : 0;
    int sum = v0 + v1 + v2 + v3;
    s[t] = sum;
    __syncthreads();
    for (int off = 1; off < 256; off <<= 1) {
        int x = (t >= off) ? s[t - off] : 0;
        __syncthreads();
        s[t] += x;
        __syncthreads();
    }
    int run = s[t] - sum;            // exclusive within block
    if (t == 255) bsum[blockIdx.x] = s[255];
    if (base + 0 < n) rp[base + 0] = run; run += v0;
    if (base + 1 < n) rp[base + 1] = run; run += v1;
    if (base + 2 < n) rp[base + 2] = run; run += v2;
    if (base + 3 < n) rp[base + 3] = run;
}

__global__ void k_scan2(int* __restrict__ bsum, int nb) {
    __shared__ int s[128];
    int t = threadIdx.x;
    int v = (t < nb) ? bsum[t] : 0;
    s[t] = v;
    __syncthreads();
    for (int off = 1; off < 128; off <<= 1) {
        int x = (t >= off) ? s[t - off] : 0;
        __syncthreads();
        s[t] += x;
        __syncthreads();
    }
    if (t < nb) bsum[t] = s[t] - v;  // exclusive block offsets
}

__global__ void k_scan3(const int* __restrict__ bsum, int* __restrict__ rp,
                        int* __restrict__ cursor, int n, int E) {
    int i = blockIdx.x * 256 + threadIdx.x;
    if (i < n) {
        int v = rp[i] + bsum[i >> 10];
        rp[i] = v;
        cursor[i] = v;
    } else if (i == n) {
        rp[n] = E;
    }
}

// ---------------- CSR fill --------------------------------------------------
__global__ void k_fill(const int* __restrict__ ei, int E, const int* __restrict__ flag,
                       int* __restrict__ cursor, int* __restrict__ csr) {
    int e = blockIdx.x * 256 + threadIdx.x;
    if (e >= E) return;
    int s, d;
    if (flag[0]) { s = ei[2 * e]; d = ei[2 * E + 2 * e]; }
    else         { s = ei[e];     d = ei[E + e]; }
    int pos = atomicAdd(&cursor[d], 1);
    csr[pos] = s;
}

// ---------------- weight/bias zero-padding ---------------------------------
__global__ void k_pad(const float* __restrict__ src, float* __restrict__ dst,
                      int KS, int NS, int ND, int total) {
    int i = blockIdx.x * 256 + threadIdx.x;
    if (i >= total) return;
    int k = i / ND, nn = i % ND;
    dst[i] = (k < KS && nn < NS) ? src[k * NS + nn] : 0.0f;
}

// ---------------- fp32 GEMM: C[M,N] = A[M,K] @ Bw[K,N] ---------------------
// BM=64, full-N tile, 256 threads as 16x16, thread tile 4 rows x (N/16) cols.
template <int N, int K>
__global__ __launch_bounds__(256) void k_gemm(const float* __restrict__ A,
                                              const float* __restrict__ Bw,
                                              float* __restrict__ C, int M) {
    constexpr int CT = N / 16;
    static_assert(CT * 16 == N, "N must be multiple of 16");
    __shared__ float xs[64][20];       // 64 rows x 16 k, pad to 20 (16B-aligned rows)
    __shared__ float ws[16 * N];
    int t = threadIdx.x;
    int tc = t & 15, tr = t >> 4;
    int row0 = blockIdx.x * 64;
    float acc[4][CT];
#pragma unroll
    for (int j = 0; j < 4; ++j)
#pragma unroll
        for (int c = 0; c < CT; ++c) acc[j][c] = 0.0f;

    int r = t >> 2, q = t & 3;
    bool rv = (row0 + r) < M;
    const float* arow = A + (size_t)(row0 + r) * K + q * 4;

    for (int kb = 0; kb < K; kb += 16) {
        float4 av = make_float4(0.f, 0.f, 0.f, 0.f);
        if (rv) av = *(const float4*)(arow + kb);
        *(float4*)&xs[r][q * 4] = av;
        const float4* bsrc = (const float4*)(Bw + (size_t)kb * N);
        float4* bdst = (float4*)ws;
#pragma unroll
        for (int j = 0; j < N / 64; ++j) bdst[t + 256 * j] = bsrc[t + 256 * j];
        __syncthreads();
#pragma unroll
        for (int k = 0; k < 16; ++k) {
            float xv[4];
#pragma unroll
            for (int j = 0; j < 4; ++j) xv[j] = xs[tr * 4 + j][k];
            float wv[CT];
#pragma unroll
            for (int c = 0; c < CT; ++c) wv[c] = ws[k * N + tc * CT + c];
#pragma unroll
            for (int j = 0; j < 4; ++j)
#pragma unroll
                for (int c = 0; c < CT; ++c) acc[j][c] += xv[j] * wv[c];
        }
        __syncthreads();
    }
#pragma unroll
    for (int j = 0; j < 4; ++j) {
        int rg = row0 + tr * 4 + j;
        if (rg < M) {
            float* crow = C + (size_t)rg * N + tc * CT;
#pragma unroll
            for (int c4 = 0; c4 < CT / 4; ++c4)
                *(float4*)(crow + c4 * 4) = make_float4(acc[j][c4 * 4 + 0], acc[j][c4 * 4 + 1],
                                                        acc[j][c4 * 4 + 2], acc[j][c4 * 4 + 3]);
        }
    }
}

// ---------------- CSR gather + norm + bias + leaky-relu --------------------
// out[i] = leaky( dinv[i]*( dinv[i]*h[i] + sum_e dinv[src]*h[src] ) + b )
template <int F4>  // features/4 (48 or 32)
__global__ __launch_bounds__(256) void k_gather(const float* __restrict__ h,
                                                const float* __restrict__ dinv,
                                                const int* __restrict__ rp,
                                                const int* __restrict__ csr,
                                                const float* __restrict__ bias,
                                                float* __restrict__ out, int n) {
    int wave = threadIdx.x >> 6, lane = threadIdx.x & 63;
    int i = blockIdx.x * 4 + wave;
    if (i >= n) return;
    const float4* H = (const float4*)h;
    float di = dinv[i];
    float4 acc = make_float4(0.f, 0.f, 0.f, 0.f);
    bool act = lane < F4;
    if (act) {
        float4 v = H[(size_t)i * F4 + lane];
        acc.x = di * v.x; acc.y = di * v.y; acc.z = di * v.z; acc.w = di * v.w;
    }
    int e0 = rp[i], e1 = rp[i + 1];
    for (int e = e0; e < e1; ++e) {
        int s = csr[e];
        float w = dinv[s];
        if (act) {
            float4 v = H[(size_t)s * F4 + lane];
            acc.x += w * v.x; acc.y += w * v.y; acc.z += w * v.z; acc.w += w * v.w;
        }
    }
    if (act) {
        float4 bb = ((const float4*)bias)[lane];
        float ox = di * acc.x + bb.x;
        float oy = di * acc.y + bb.y;
        float oz = di * acc.z + bb.z;
        float ow = di * acc.w + bb.w;
        ox = ox >= 0.f ? ox : 0.01f * ox;
        oy = oy >= 0.f ? oy : 0.01f * oy;
        oz = oz >= 0.f ? oz : 0.01f * oz;
        ow = ow >= 0.f ? ow : 0.01f * ow;
        ((float4*)out)[(size_t)i * F4 + lane] = make_float4(ox, oy, oz, ow);
    }
}

// ---------------- final GEMM (K=128 -> 40 classes) + log_softmax -----------
__global__ __launch_bounds__(256) void k_out(const float* __restrict__ H,
                                             const float* __restrict__ W3p,  // [128][64] padded
                                             const float* __restrict__ b3,
                                             float* __restrict__ out, int M) {
    __shared__ float w[H2P * NCP];
    int t = threadIdx.x;
    {
        const float4* src = (const float4*)W3p;
        float4* dst = (float4*)w;
#pragma unroll
        for (int j = 0; j < (H2P * NCP / 4) / 256; ++j) dst[t + 256 * j] = src[t + 256 * j];
    }
    __syncthreads();
    int wave = t >> 6, lane = t & 63;
    float bias = (lane < NC) ? b3[lane] : -__builtin_inff();
    for (int rr = blockIdx.x * 4 + wave; rr < M; rr += gridDim.x * 4) {
        const float4* hr = (const float4*)(H + (size_t)rr * H2P);
        float acc = 0.f;
#pragma unroll
        for (int kq = 0; kq < H2P / 4; ++kq) {
            float4 hv = hr[kq];
            acc += hv.x * w[(kq * 4 + 0) * NCP + lane];
            acc += hv.y * w[(kq * 4 + 1) * NCP + lane];
            acc += hv.z * w[(kq * 4 + 2) * NCP + lane];
            acc += hv.w * w[(kq * 4 + 3) * NCP + lane];
        }
        float logit = acc + bias;   // pad lanes: -inf
        float m = logit;
#pragma unroll
        for (int d = 1; d < 64; d <<= 1) m = fmaxf(m, __shfl_xor(m, d));
        float p = expf(logit - m);  // pad lanes: exp(-inf)=0
        float ssum = p;
#pragma unroll
        for (int d = 1; d < 64; d <<= 1) ssum += __shfl_xor(ssum, d);
        float res = logit - m - logf(ssum);
        if (lane < NC) out[(size_t)rr * NC + lane] = res;
    }
}

// ---------------------------------------------------------------------------
extern "C" void kernel_launch(void* const* d_in, const int* in_sizes, int n_in,
                              void* d_out, int out_size, void* d_ws, size_t ws_size,
                              hipStream_t stream) {
    const float* x  = (const float*)d_in[0];
    const int*   ei = (const int*)d_in[1];
    const float* W1 = (const float*)d_in[2];
    const float* b1 = (const float*)d_in[3];
    const float* W2 = (const float*)d_in[4];
    const float* b2 = (const float*)d_in[5];
    const float* W3 = (const float*)d_in[6];
    const float* b3 = (const float*)d_in[7];
    float* outp = (float*)d_out;

    int n = in_sizes[0] / F_IN;   // 100000
    int E = in_sizes[1] / 2;      // 1600000

    char* p = (char*)d_ws;
    auto alloc = [&](size_t bytes) -> char* {
        char* r = p;
        p += (bytes + 511) & ~(size_t)511;
        return r;
    };
    int*   flag   = (int*)alloc(4);
    int*   deg    = (int*)alloc((size_t)n * 4);
    float* dinv   = (float*)alloc((size_t)n * 4);
    int*   rp     = (int*)alloc((size_t)(n + 1) * 4);
    int*   cursor = (int*)alloc((size_t)n * 4);
    int*   bsum   = (int*)alloc(4096);
    int*   csr    = (int*)alloc((size_t)E * 4);
    float* W1p    = (float*)alloc((size_t)F_IN * H1P * 4);
    float* W2p    = (float*)alloc((size_t)H1P * H2P * 4);
    float* W3p    = (float*)alloc((size_t)H2P * NCP * 4);
    float* b1p    = (float*)alloc(H1P * 4);
    float* b2p    = (float*)alloc(H2P * 4);
    float* bufA   = (float*)alloc((size_t)n * H1P * 4);   // h1 / h2
    float* bufB   = (float*)alloc((size_t)n * H1P * 4);   // hagg1 / hagg2

    hipMemsetAsync(flag, 1, 4, stream);   // assume int64 until disproven
    hipMemsetAsync(deg, 0, (size_t)n * 4, stream);

    k_detect<<<16, 256, 0, stream>>>(ei, flag);

    int eb = (E + 255) / 256;
    k_hist<<<eb, 256, 0, stream>>>(ei, E, flag, deg);
    k_dinv<<<(n + 255) / 256, 256, 0, stream>>>(deg, dinv, n);

    int nb = (n + 1023) / 1024;   // 98
    k_scan1<<<nb, 256, 0, stream>>>(deg, rp, bsum, n);
    k_scan2<<<1, 128, 0, stream>>>(bsum, nb);
    k_scan3<<<(n + 1 + 255) / 256, 256, 0, stream>>>(bsum, rp, cursor, n, E);
    k_fill<<<eb, 256, 0, stream>>>(ei, E, flag, cursor, csr);

    // padded weights/biases
    k_pad<<<(F_IN * H1P + 255) / 256, 256, 0, stream>>>(W1, W1p, F_IN, H1V, H1P, F_IN * H1P);
    k_pad<<<(H1P * H2P + 255) / 256, 256, 0, stream>>>(W2, W2p, H1V, H2V, H2P, H1P * H2P);
    k_pad<<<(H2P * NCP + 255) / 256, 256, 0, stream>>>(W3, W3p, H2V, NC, NCP, H2P * NCP);
    k_pad<<<1, 256, 0, stream>>>(b1, b1p, 1, H1V, H1P, H1P);
    k_pad<<<1, 256, 0, stream>>>(b2, b2p, 1, H2V, H2P, H2P);

    int gb = (n + 63) / 64;
    // layer 1
    k_gemm<H1P, F_IN><<<gb, 256, 0, stream>>>(x, W1p, bufA, n);
    k_gather<H1P / 4><<<(n + 3) / 4, 256, 0, stream>>>(bufA, dinv, rp, csr, b1p, bufB, n);
    // layer 2
    k_gemm<H2P, H1P><<<gb, 256, 0, stream>>>(bufB, W2p, bufA, n);
    k_gather<H2P / 4><<<(n + 3) / 4, 256, 0, stream>>>(bufA, dinv, rp, csr, b2p, bufB, n);
    // output layer + log_softmax
    k_out<<<4096, 256, 0, stream>>>(bufB, W3p, b3, outp, n);
}

// Round 2
// 704.570 us; speedup vs baseline: 1.5172x; 1.5172x over previous
//
#include <hip/hip_runtime.h>
#include <math.h>

typedef __attribute__((ext_vector_type(8))) short short8;
typedef __attribute__((ext_vector_type(4))) float f32x4;

static constexpr int F_IN = 512;
static constexpr int H1V = 180, H1P = 192;
static constexpr int H2V = 120, H2P = 128;
static constexpr int NC  = 40,  NCP = 64;

__device__ inline unsigned f2bf(float f) {
    unsigned u = __float_as_uint(f);
    return (u + 0x7fffu + ((u >> 16) & 1u)) >> 16;   // RNE
}
__device__ inline unsigned cvtpk(float lo, float hi) {
    unsigned r;
    asm("v_cvt_pk_bf16_f32 %0, %1, %2" : "=v"(r) : "v"(lo), "v"(hi));
    return r;
}
#define BLO(u) __uint_as_float((u) << 16)
#define BHI(u) __uint_as_float((u) & 0xffff0000u)

// ---------------- edge dtype detection (int32 vs int64 layout) -------------
__global__ void k_detect(const int* __restrict__ ei, int* __restrict__ flag) {
    int i = blockIdx.x * 256 + threadIdx.x;
    if (ei[2 * i + 1] != 0) flag[0] = 0;
}

// ---------------- degree histogram + dinv ----------------------------------
__global__ void k_hist(const int* __restrict__ ei, int E, const int* __restrict__ flag,
                       int* __restrict__ deg) {
    int e = blockIdx.x * 256 + threadIdx.x;
    if (e >= E) return;
    int d = flag[0] ? ei[2 * E + 2 * e] : ei[E + e];
    atomicAdd(&deg[d], 1);
}

__global__ void k_dinv(const int* __restrict__ deg, float* __restrict__ dinv, int n) {
    int i = blockIdx.x * 256 + threadIdx.x;
    if (i < n) dinv[i] = rsqrtf((float)(deg[i] + 1));
}

// ---------------- exclusive scan (3-kernel) --------------------------------
__global__ void k_scan1(const int* __restrict__ deg, int* __restrict__ rp,
                        int* __restrict__ bsum, int n) {
    __shared__ int s[256];
    int t = threadIdx.x;
    int base = blockIdx.x * 1024 + t * 4;
    int v0 = (base + 0 < n) ? deg[base + 0] : 0;
    int v1 = (base + 1 < n) ? deg[base + 1] : 0;
    int v2 = (base + 2 < n) ? deg[base + 2] : 0;
    int v3 = (base + 3 < n) ? deg[base + 3] : 0;
    int sum = v0 + v1 + v2 + v3;
    s[t] = sum;
    __syncthreads();
    for (int off = 1; off < 256; off <<= 1) {
        int x = (t >= off) ? s[t - off] : 0;
        __syncthreads();
        s[t] += x;
        __syncthreads();
    }
    int run = s[t] - sum;
    if (t == 255) bsum[blockIdx.x] = s[255];
    if (base + 0 < n) rp[base + 0] = run; run += v0;
    if (base + 1 < n) rp[base + 1] = run; run += v1;
    if (base + 2 < n) rp[base + 2] = run; run += v2;
    if (base + 3 < n) rp[base + 3] = run;
}

__global__ void k_scan2(int* __restrict__ bsum, int nb) {
    __shared__ int s[128];
    int t = threadIdx.x;
    int v = (t < nb) ? bsum[t] : 0;
    s[t] = v;
    __syncthreads();
    for (int off = 1; off < 128; off <<= 1) {
        int x = (t >= off) ? s[t - off] : 0;
        __syncthreads();
        s[t] += x;
        __syncthreads();
    }
    if (t < nb) bsum[t] = s[t] - v;
}

__global__ void k_scan3(const int* __restrict__ bsum, int* __restrict__ rp,
                        int* __restrict__ cursor, int n, int E) {
    int i = blockIdx.x * 256 + threadIdx.x;
    if (i < n) {
        int v = rp[i] + bsum[i >> 10];
        rp[i] = v;
        cursor[i] = v;
    } else if (i == n) {
        rp[n] = E;
    }
}

// ---------------- CSR fill --------------------------------------------------
__global__ void k_fill(const int* __restrict__ ei, int E, const int* __restrict__ flag,
                       int* __restrict__ cursor, int* __restrict__ csr) {
    int e = blockIdx.x * 256 + threadIdx.x;
    if (e >= E) return;
    int s, d;
    if (flag[0]) { s = ei[2 * e]; d = ei[2 * E + 2 * e]; }
    else         { s = ei[e];     d = ei[E + e]; }
    int pos = atomicAdd(&cursor[d], 1);
    csr[pos] = s;
}

// ---------------- fp32 zero-pad (W3, biases) -------------------------------
__global__ void k_pad(const float* __restrict__ src, float* __restrict__ dst,
                      int KS, int NS, int ND, int total) {
    int i = blockIdx.x * 256 + threadIdx.x;
    if (i >= total) return;
    int k = i / ND, nn = i % ND;
    dst[i] = (k < KS && nn < NS) ? src[k * NS + nn] : 0.0f;
}

// ---------------- bf16 MFMA B-fragment staging -----------------------------
// dst[(k>>3)*ND*8 + c*8 + (k&7)] = bf16(src[k][c]) with zero pad
__global__ void k_prepw(const float* __restrict__ src, unsigned short* __restrict__ dst,
                        int KS, int NS, int KD, int ND) {
    int i = blockIdx.x * 256 + threadIdx.x;
    if (i >= KD * ND) return;
    int k = i / ND, c = i % ND;
    float v = (k < KS && c < NS) ? src[k * NS + c] : 0.0f;
    dst[(size_t)(k >> 3) * ND * 8 + c * 8 + (k & 7)] = (unsigned short)f2bf(v);
}

// ---------------- GEMM1: h1' = dinv * (x @ W1), bf16 MFMA, LDS-free --------
// BM=64 (4 row frags), N=192 (wave w owns cols w*48..w*48+48 = 3 col frags)
__global__ __launch_bounds__(256) void k_gemm1(const float* __restrict__ X,
                                               const short8* __restrict__ Bs,
                                               const float* __restrict__ dinv,
                                               unsigned short* __restrict__ Hout,
                                               int M) {
    int t = threadIdx.x;
    int w = t >> 6, l = t & 63;
    int lr = l & 15, kg = l >> 4;
    int row0 = blockIdx.x * 64;
    int colb = w * 48;
    f32x4 acc[4][3];
#pragma unroll
    for (int m = 0; m < 4; ++m)
#pragma unroll
        for (int nn = 0; nn < 3; ++nn) acc[m][nn] = (f32x4){0.f, 0.f, 0.f, 0.f};

    int rbase[4];
#pragma unroll
    for (int m = 0; m < 4; ++m) {
        int r = row0 + m * 16 + lr;
        rbase[m] = r < M ? r : M - 1;
    }

    for (int kb = 0; kb < F_IN; kb += 32) {
        short8 b[3];
#pragma unroll
        for (int nn = 0; nn < 3; ++nn)
            b[nn] = Bs[(size_t)((kb >> 3) + kg) * H1P + colb + nn * 16 + lr];
        short8 a[4];
#pragma unroll
        for (int m = 0; m < 4; ++m) {
            const float4* pa = (const float4*)(X + (size_t)rbase[m] * F_IN + kb + kg * 8);
            float4 v0 = pa[0];
            float4 v1 = pa[1];
            union { unsigned u[4]; short8 s; } cu;
            cu.u[0] = cvtpk(v0.x, v0.y);
            cu.u[1] = cvtpk(v0.z, v0.w);
            cu.u[2] = cvtpk(v1.x, v1.y);
            cu.u[3] = cvtpk(v1.z, v1.w);
            a[m] = cu.s;
        }
#pragma unroll
        for (int m = 0; m < 4; ++m)
#pragma unroll
            for (int nn = 0; nn < 3; ++nn)
                acc[m][nn] = __builtin_amdgcn_mfma_f32_16x16x32_bf16(a[m], b[nn], acc[m][nn], 0, 0, 0);
    }
#pragma unroll
    for (int m = 0; m < 4; ++m) {
        int r4 = row0 + m * 16 + kg * 4;
#pragma unroll
        for (int j = 0; j < 4; ++j) {
            int grow = r4 + j;
            if (grow < M) {
                float dv = dinv[grow];
#pragma unroll
                for (int nn = 0; nn < 3; ++nn) {
                    float vv = acc[m][nn][j] * dv;
                    Hout[(size_t)grow * H1P + colb + nn * 16 + lr] = (unsigned short)f2bf(vv);
                }
            }
        }
    }
}

// ---------------- GEMM2: h2' = dinv * (h1agg @ W2), bf16 in, bf16 out ------
// BM=64, N=128 (wave w owns cols w*32 = 2 col frags), K=192
__global__ __launch_bounds__(256) void k_gemm2(const unsigned short* __restrict__ A,
                                               const short8* __restrict__ Bs,
                                               const float* __restrict__ dinv,
                                               unsigned short* __restrict__ Hout,
                                               int M) {
    int t = threadIdx.x;
    int w = t >> 6, l = t & 63;
    int lr = l & 15, kg = l >> 4;
    int row0 = blockIdx.x * 64;
    int colb = w * 32;
    f32x4 acc[4][2];
#pragma unroll
    for (int m = 0; m < 4; ++m)
#pragma unroll
        for (int nn = 0; nn < 2; ++nn) acc[m][nn] = (f32x4){0.f, 0.f, 0.f, 0.f};

    int rbase[4];
#pragma unroll
    for (int m = 0; m < 4; ++m) {
        int r = row0 + m * 16 + lr;
        rbase[m] = r < M ? r : M - 1;
    }

    for (int kb = 0; kb < H1P; kb += 32) {
        short8 b[2];
#pragma unroll
        for (int nn = 0; nn < 2; ++nn)
            b[nn] = Bs[(size_t)((kb >> 3) + kg) * H2P + colb + nn * 16 + lr];
        short8 a[4];
#pragma unroll
        for (int m = 0; m < 4; ++m)
            a[m] = *(const short8*)(A + (size_t)rbase[m] * H1P + kb + kg * 8);
#pragma unroll
        for (int m = 0; m < 4; ++m)
#pragma unroll
            for (int nn = 0; nn < 2; ++nn)
                acc[m][nn] = __builtin_amdgcn_mfma_f32_16x16x32_bf16(a[m], b[nn], acc[m][nn], 0, 0, 0);
    }
#pragma unroll
    for (int m = 0; m < 4; ++m) {
        int r4 = row0 + m * 16 + kg * 4;
#pragma unroll
        for (int j = 0; j < 4; ++j) {
            int grow = r4 + j;
            if (grow < M) {
                float dv = dinv[grow];
#pragma unroll
                for (int nn = 0; nn < 2; ++nn) {
                    float vv = acc[m][nn][j] * dv;
                    Hout[(size_t)grow * H2P + colb + nn * 16 + lr] = (unsigned short)f2bf(vv);
                }
            }
        }
    }
}

// ---------------- CSR gather on bf16 h' rows -------------------------------
// out[i] = leaky( dinv[i] * (h'[i] + sum_{s in N(i)} h'[s]) + b )
// CH = number of 8B (4-elem) chunks per row (48 for 192, 32 for 128)
template <int CH, int OUTBF>
__global__ __launch_bounds__(256) void k_gat(const uint2* __restrict__ H,
                                             const float* __restrict__ dinv,
                                             const int* __restrict__ rp,
                                             const int* __restrict__ csr,
                                             const float* __restrict__ bias,
                                             void* __restrict__ outv, int n) {
    int wv = threadIdx.x >> 6, l = threadIdx.x & 63;
    int i = blockIdx.x * 4 + wv;
    if (i >= n) return;
    bool act = l < CH;
    int c = act ? l : 0;
    const uint2* Hr = H + c;

    float a0, a1, a2, a3;
    {
        uint2 v = Hr[(size_t)i * CH];
        a0 = BLO(v.x); a1 = BHI(v.x); a2 = BLO(v.y); a3 = BHI(v.y);
    }
    float p0 = 0.f, p1 = 0.f, p2 = 0.f, p3 = 0.f;

    int e0 = rp[i], e1 = rp[i + 1];
    int e = e0;
    for (; e + 1 < e1; e += 2) {
        int s0 = csr[e], s1 = csr[e + 1];
        uint2 va = Hr[(size_t)s0 * CH];
        uint2 vb = Hr[(size_t)s1 * CH];
        a0 += BLO(va.x); a1 += BHI(va.x); a2 += BLO(va.y); a3 += BHI(va.y);
        p0 += BLO(vb.x); p1 += BHI(vb.x); p2 += BLO(vb.y); p3 += BHI(vb.y);
    }
    if (e < e1) {
        int s0 = csr[e];
        uint2 va = Hr[(size_t)s0 * CH];
        a0 += BLO(va.x); a1 += BHI(va.x); a2 += BLO(va.y); a3 += BHI(va.y);
    }
    a0 += p0; a1 += p1; a2 += p2; a3 += p3;

    float di = dinv[i];
    float4 bb = *(const float4*)(bias + 4 * c);
    float o0 = fmaf(di, a0, bb.x);
    float o1 = fmaf(di, a1, bb.y);
    float o2 = fmaf(di, a2, bb.z);
    float o3 = fmaf(di, a3, bb.w);
    o0 = o0 >= 0.f ? o0 : 0.01f * o0;
    o1 = o1 >= 0.f ? o1 : 0.01f * o1;
    o2 = o2 >= 0.f ? o2 : 0.01f * o2;
    o3 = o3 >= 0.f ? o3 : 0.01f * o3;
    if (act) {
        if (OUTBF) {
            uint2 r;
            r.x = (f2bf(o1) << 16) | f2bf(o0);
            r.y = (f2bf(o3) << 16) | f2bf(o2);
            ((uint2*)outv)[(size_t)i * CH + c] = r;
        } else {
            ((float4*)outv)[(size_t)i * CH + c] = make_float4(o0, o1, o2, o3);
        }
    }
}

// ---------------- final layer + log_softmax (fp32) -------------------------
__global__ __launch_bounds__(256) void k_out(const float* __restrict__ H,
                                             const float* __restrict__ W3p,
                                             const float* __restrict__ b3,
                                             float* __restrict__ out, int M) {
    __shared__ float w[H2P * NCP];
    int t = threadIdx.x;
    {
        const float4* src = (const float4*)W3p;
        float4* dst = (float4*)w;
#pragma unroll
        for (int j = 0; j < (H2P * NCP / 4) / 256; ++j) dst[t + 256 * j] = src[t + 256 * j];
    }
    __syncthreads();
    int wave = t >> 6, lane = t & 63;
    float bias = (lane < NC) ? b3[lane] : -__builtin_inff();
    for (int rr = blockIdx.x * 4 + wave; rr < M; rr += gridDim.x * 4) {
        const float4* hr = (const float4*)(H + (size_t)rr * H2P);
        float acc = 0.f;
#pragma unroll
        for (int kq = 0; kq < H2P / 4; ++kq) {
            float4 hv = hr[kq];
            acc += hv.x * w[(kq * 4 + 0) * NCP + lane];
            acc += hv.y * w[(kq * 4 + 1) * NCP + lane];
            acc += hv.z * w[(kq * 4 + 2) * NCP + lane];
            acc += hv.w * w[(kq * 4 + 3) * NCP + lane];
        }
        float logit = acc + bias;
        float m = logit;
#pragma unroll
        for (int d = 1; d < 64; d <<= 1) m = fmaxf(m, __shfl_xor(m, d));
        float p = expf(logit - m);
        float ssum = p;
#pragma unroll
        for (int d = 1; d < 64; d <<= 1) ssum += __shfl_xor(ssum, d);
        float res = logit - m - logf(ssum);
        if (lane < NC) out[(size_t)rr * NC + lane] = res;
    }
}

// ---------------------------------------------------------------------------
extern "C" void kernel_launch(void* const* d_in, const int* in_sizes, int n_in,
                              void* d_out, int out_size, void* d_ws, size_t ws_size,
                              hipStream_t stream) {
    const float* x  = (const float*)d_in[0];
    const int*   ei = (const int*)d_in[1];
    const float* W1 = (const float*)d_in[2];
    const float* b1 = (const float*)d_in[3];
    const float* W2 = (const float*)d_in[4];
    const float* b2 = (const float*)d_in[5];
    const float* W3 = (const float*)d_in[6];
    const float* b3 = (const float*)d_in[7];
    float* outp = (float*)d_out;

    int n = in_sizes[0] / F_IN;   // 100000
    int E = in_sizes[1] / 2;      // 1600000

    char* p = (char*)d_ws;
    auto alloc = [&](size_t bytes) -> char* {
        char* r = p;
        p += (bytes + 511) & ~(size_t)511;
        return r;
    };
    int*            flag   = (int*)alloc(4);
    int*            deg    = (int*)alloc((size_t)n * 4);
    float*          dinv   = (float*)alloc((size_t)n * 4);
    int*            rp     = (int*)alloc((size_t)(n + 1) * 4);
    int*            cursor = (int*)alloc((size_t)n * 4);
    int*            bsum   = (int*)alloc(4096);
    int*            csr    = (int*)alloc((size_t)E * 4);
    unsigned short* W1s    = (unsigned short*)alloc((size_t)F_IN * H1P * 2);
    unsigned short* W2s    = (unsigned short*)alloc((size_t)H1P * H2P * 2);
    float*          W3p    = (float*)alloc((size_t)H2P * NCP * 4);
    float*          b1p    = (float*)alloc(H1P * 4);
    float*          b2p    = (float*)alloc(H2P * 4);
    unsigned short* h1     = (unsigned short*)alloc((size_t)n * H1P * 2);
    unsigned short* h1agg  = (unsigned short*)alloc((size_t)n * H1P * 2);
    unsigned short* h2     = (unsigned short*)alloc((size_t)n * H2P * 2);
    float*          h2agg  = (float*)alloc((size_t)n * H2P * 4);

    hipMemsetAsync(flag, 1, 4, stream);
    hipMemsetAsync(deg, 0, (size_t)n * 4, stream);

    k_detect<<<16, 256, 0, stream>>>(ei, flag);

    int eb = (E + 255) / 256;
    k_hist<<<eb, 256, 0, stream>>>(ei, E, flag, deg);
    k_dinv<<<(n + 255) / 256, 256, 0, stream>>>(deg, dinv, n);

    int nb = (n + 1023) / 1024;
    k_scan1<<<nb, 256, 0, stream>>>(deg, rp, bsum, n);
    k_scan2<<<1, 128, 0, stream>>>(bsum, nb);
    k_scan3<<<(n + 1 + 255) / 256, 256, 0, stream>>>(bsum, rp, cursor, n, E);
    k_fill<<<eb, 256, 0, stream>>>(ei, E, flag, cursor, csr);

    k_prepw<<<(F_IN * H1P + 255) / 256, 256, 0, stream>>>(W1, W1s, F_IN, H1V, F_IN, H1P);
    k_prepw<<<(H1P * H2P + 255) / 256, 256, 0, stream>>>(W2, W2s, H1V, H2V, H1P, H2P);
    k_pad<<<(H2P * NCP + 255) / 256, 256, 0, stream>>>(W3, W3p, H2V, NC, NCP, H2P * NCP);
    k_pad<<<1, 256, 0, stream>>>(b1, b1p, 1, H1V, H1P, H1P);
    k_pad<<<1, 256, 0, stream>>>(b2, b2p, 1, H2V, H2P, H2P);

    int gb = (n + 63) / 64;
    // layer 1
    k_gemm1<<<gb, 256, 0, stream>>>(x, (const short8*)W1s, dinv, h1, n);
    k_gat<H1P / 4, 1><<<(n + 3) / 4, 256, 0, stream>>>((const uint2*)h1, dinv, rp, csr, b1p, h1agg, n);
    // layer 2
    k_gemm2<<<gb, 256, 0, stream>>>(h1agg, (const short8*)W2s, dinv, h2, n);
    k_gat<H2P / 4, 0><<<(n + 3) / 4, 256, 0, stream>>>((const uint2*)h2, dinv, rp, csr, b2p, h2agg, n);
    // output layer + log_softmax
    k_out<<<4096, 256, 0, stream>>>(h2agg, W3p, b3, outp, n);
}

// Round 3
// 600.268 us; speedup vs baseline: 1.7808x; 1.1738x over previous
//
#include <hip/hip_runtime.h>
#include <math.h>

typedef __attribute__((ext_vector_type(8))) short short8;
typedef __attribute__((ext_vector_type(4))) float f32x4;

static constexpr int F_IN = 512;
static constexpr int H1V = 180, H1P = 192;
static constexpr int H2V = 120, H2P = 128;
static constexpr int NC  = 40,  NCP = 64;

__device__ inline unsigned f2bf(float f) {
    unsigned u = __float_as_uint(f);
    return (u + 0x7fffu + ((u >> 16) & 1u)) >> 16;   // RNE
}
__device__ inline unsigned cvtpk(float lo, float hi) {
    unsigned r;
    asm("v_cvt_pk_bf16_f32 %0, %1, %2" : "=v"(r) : "v"(lo), "v"(hi));
    return r;
}
#define BLO(u) __uint_as_float((u) << 16)
#define BHI(u) __uint_as_float((u) & 0xffff0000u)

__device__ inline void gload_lds16(const void* gsrc, void* ldst) {
    __builtin_amdgcn_global_load_lds(
        (const __attribute__((address_space(1))) void*)gsrc,
        (__attribute__((address_space(3))) void*)ldst, 16, 0, 0);
}

// ---------------- edge dtype detection (int32 vs int64 layout) -------------
__global__ void k_detect(const int* __restrict__ ei, int* __restrict__ flag) {
    int i = blockIdx.x * 256 + threadIdx.x;
    if (ei[2 * i + 1] != 0) flag[0] = 0;
}

// ---------------- degree histogram + dinv ----------------------------------
__global__ void k_hist(const int* __restrict__ ei, int E, const int* __restrict__ flag,
                       int* __restrict__ deg) {
    int e = blockIdx.x * 256 + threadIdx.x;
    if (e >= E) return;
    int d = flag[0] ? ei[2 * E + 2 * e] : ei[E + e];
    atomicAdd(&deg[d], 1);
}

__global__ void k_dinv(const int* __restrict__ deg, float* __restrict__ dinv, int n) {
    int i = blockIdx.x * 256 + threadIdx.x;
    if (i < n) dinv[i] = rsqrtf((float)(deg[i] + 1));
}

// ---------------- exclusive scan (3-kernel) --------------------------------
__global__ void k_scan1(const int* __restrict__ deg, int* __restrict__ rp,
                        int* __restrict__ bsum, int n) {
    __shared__ int s[256];
    int t = threadIdx.x;
    int base = blockIdx.x * 1024 + t * 4;
    int v0 = (base + 0 < n) ? deg[base + 0] : 0;
    int v1 = (base + 1 < n) ? deg[base + 1] : 0;
    int v2 = (base + 2 < n) ? deg[base + 2] : 0;
    int v3 = (base + 3 < n) ? deg[base + 3] : 0;
    int sum = v0 + v1 + v2 + v3;
    s[t] = sum;
    __syncthreads();
    for (int off = 1; off < 256; off <<= 1) {
        int x = (t >= off) ? s[t - off] : 0;
        __syncthreads();
        s[t] += x;
        __syncthreads();
    }
    int run = s[t] - sum;
    if (t == 255) bsum[blockIdx.x] = s[255];
    if (base + 0 < n) rp[base + 0] = run; run += v0;
    if (base + 1 < n) rp[base + 1] = run; run += v1;
    if (base + 2 < n) rp[base + 2] = run; run += v2;
    if (base + 3 < n) rp[base + 3] = run;
}

__global__ void k_scan2(int* __restrict__ bsum, int nb) {
    __shared__ int s[128];
    int t = threadIdx.x;
    int v = (t < nb) ? bsum[t] : 0;
    s[t] = v;
    __syncthreads();
    for (int off = 1; off < 128; off <<= 1) {
        int x = (t >= off) ? s[t - off] : 0;
        __syncthreads();
        s[t] += x;
        __syncthreads();
    }
    if (t < nb) bsum[t] = s[t] - v;
}

__global__ void k_scan3(const int* __restrict__ bsum, int* __restrict__ rp,
                        int* __restrict__ cursor, int n, int E) {
    int i = blockIdx.x * 256 + threadIdx.x;
    if (i < n) {
        int v = rp[i] + bsum[i >> 10];
        rp[i] = v;
        cursor[i] = v;
    } else if (i == n) {
        rp[n] = E;
    }
}

// ---------------- CSR fill --------------------------------------------------
__global__ void k_fill(const int* __restrict__ ei, int E, const int* __restrict__ flag,
                       int* __restrict__ cursor, int* __restrict__ csr) {
    int e = blockIdx.x * 256 + threadIdx.x;
    if (e >= E) return;
    int s, d;
    if (flag[0]) { s = ei[2 * e]; d = ei[2 * E + 2 * e]; }
    else         { s = ei[e];     d = ei[E + e]; }
    int pos = atomicAdd(&cursor[d], 1);
    csr[pos] = s;
}

// ---------------- fp32 zero-pad (W3, biases) -------------------------------
__global__ void k_pad(const float* __restrict__ src, float* __restrict__ dst,
                      int KS, int NS, int ND, int total) {
    int i = blockIdx.x * 256 + threadIdx.x;
    if (i >= total) return;
    int k = i / ND, nn = i % ND;
    dst[i] = (k < KS && nn < NS) ? src[k * NS + nn] : 0.0f;
}

// ---------------- bf16 MFMA B-fragment staging -----------------------------
__global__ void k_prepw(const float* __restrict__ src, unsigned short* __restrict__ dst,
                        int KS, int NS, int KD, int ND) {
    int i = blockIdx.x * 256 + threadIdx.x;
    if (i >= KD * ND) return;
    int k = i / ND, c = i % ND;
    float v = (k < KS && c < NS) ? src[k * NS + c] : 0.0f;
    dst[(size_t)(k >> 3) * ND * 8 + c * 8 + (k & 7)] = (unsigned short)f2bf(v);
}

// ---------------- GEMM1: h1' = dinv * (x @ W1) -----------------------------
// BM=128, BK=32 fp32, 512 thr (wave grid 2Mx4N), dbuf LDS via global_load_lds,
// XOR-swizzled 16B chunks (slot c' = c ^ (row&7)) to kill bank conflicts.
__global__ __launch_bounds__(512) void k_gemm1(const float* __restrict__ X,
                                               const short8* __restrict__ Bs,
                                               const float* __restrict__ dinv,
                                               unsigned short* __restrict__ Hout,
                                               int M) {
    __shared__ float ldsf[8192];   // 2 x 16 KB
    char* lds = (char*)ldsf;
    int t = threadIdx.x;
    int w = t >> 6, l = t & 63;
    int lr = l & 15, kg = l >> 4;
    int wr = w >> 2, wc = w & 3;
    int row0 = blockIdx.x * 128;
    int colb = wc * 48;

    f32x4 acc[4][3];
#pragma unroll
    for (int m = 0; m < 4; ++m)
#pragma unroll
        for (int nn = 0; nn < 3; ++nn) acc[m][nn] = (f32x4){0.f, 0.f, 0.f, 0.f};

    auto stage = [&](int kb, int buf) {
#pragma unroll
        for (int j = 0; j < 2; ++j) {
            int o = j * 8192 + t * 16;                // byte offset in tile
            int row = o >> 7;                         // 128 B per row (32 f32)
            int col4 = ((o >> 4) & 7) ^ (row & 7);    // inverse-swizzled source chunk
            int rowg = row0 + row;
            if (rowg >= M) rowg = M - 1;
            gload_lds16(X + (size_t)rowg * F_IN + kb + col4 * 4,
                        lds + buf * 16384 + j * 8192 + w * 1024);
        }
    };

    stage(0, 0);
    __syncthreads();

    for (int ts = 0; ts < 16; ++ts) {
        int cur = ts & 1;
        if (ts < 15) stage((ts + 1) * 32, cur ^ 1);
        short8 b[3];
#pragma unroll
        for (int nn = 0; nn < 3; ++nn)
            b[nn] = Bs[(size_t)(ts * 4 + kg) * H1P + colb + nn * 16 + lr];
        short8 a[4];
#pragma unroll
        for (int m = 0; m < 4; ++m) {
            int row = wr * 64 + m * 16 + lr;
            char* base = lds + cur * 16384 + row * 128;
            float4 v0 = *(const float4*)(base + (((2 * kg + 0) ^ (row & 7)) * 16));
            float4 v1 = *(const float4*)(base + (((2 * kg + 1) ^ (row & 7)) * 16));
            union { unsigned u[4]; short8 s; } cu;
            cu.u[0] = cvtpk(v0.x, v0.y);
            cu.u[1] = cvtpk(v0.z, v0.w);
            cu.u[2] = cvtpk(v1.x, v1.y);
            cu.u[3] = cvtpk(v1.z, v1.w);
            a[m] = cu.s;
        }
#pragma unroll
        for (int m = 0; m < 4; ++m)
#pragma unroll
            for (int nn = 0; nn < 3; ++nn)
                acc[m][nn] = __builtin_amdgcn_mfma_f32_16x16x32_bf16(a[m], b[nn], acc[m][nn], 0, 0, 0);
        __syncthreads();
    }

#pragma unroll
    for (int m = 0; m < 4; ++m) {
        int r4 = row0 + wr * 64 + m * 16 + kg * 4;
#pragma unroll
        for (int j = 0; j < 4; ++j) {
            int grow = r4 + j;
            if (grow < M) {
                float dv = dinv[grow];
#pragma unroll
                for (int nn = 0; nn < 3; ++nn)
                    Hout[(size_t)grow * H1P + colb + nn * 16 + lr] =
                        (unsigned short)f2bf(acc[m][nn][j] * dv);
            }
        }
    }
}

// ---------------- GEMM2: h2' = dinv * (h1agg @ W2), bf16 in ---------------
// BM=128, BK=64 bf16 (128 B rows), 3 k-iterations, same swizzle scheme.
__global__ __launch_bounds__(512) void k_gemm2(const unsigned short* __restrict__ A,
                                               const short8* __restrict__ Bs,
                                               const float* __restrict__ dinv,
                                               unsigned short* __restrict__ Hout,
                                               int M) {
    __shared__ unsigned short ldsu[16384];   // 2 x 16 KB
    char* lds = (char*)ldsu;
    int t = threadIdx.x;
    int w = t >> 6, l = t & 63;
    int lr = l & 15, kg = l >> 4;
    int wr = w >> 2, wc = w & 3;
    int row0 = blockIdx.x * 128;
    int colb = wc * 32;

    f32x4 acc[4][2];
#pragma unroll
    for (int m = 0; m < 4; ++m)
#pragma unroll
        for (int nn = 0; nn < 2; ++nn) acc[m][nn] = (f32x4){0.f, 0.f, 0.f, 0.f};

    auto stage = [&](int kb, int buf) {
#pragma unroll
        for (int j = 0; j < 2; ++j) {
            int o = j * 8192 + t * 16;                // byte offset in tile
            int row = o >> 7;                         // 128 B per row (64 bf16)
            int chunk = ((o >> 4) & 7) ^ (row & 7);   // inverse-swizzled source chunk
            int rowg = row0 + row;
            if (rowg >= M) rowg = M - 1;
            gload_lds16(A + (size_t)rowg * H1P + kb + chunk * 8,
                        lds + buf * 16384 + j * 8192 + w * 1024);
        }
    };

    stage(0, 0);
    __syncthreads();

    for (int ts = 0; ts < 3; ++ts) {
        int cur = ts & 1;
        if (ts < 2) stage((ts + 1) * 64, cur ^ 1);
        short8 b[2][2];
#pragma unroll
        for (int kk = 0; kk < 2; ++kk)
#pragma unroll
            for (int nn = 0; nn < 2; ++nn)
                b[kk][nn] = Bs[(size_t)(ts * 8 + kk * 4 + kg) * H2P + colb + nn * 16 + lr];
        short8 a[2][4];
#pragma unroll
        for (int kk = 0; kk < 2; ++kk)
#pragma unroll
            for (int m = 0; m < 4; ++m) {
                int row = wr * 64 + m * 16 + lr;
                a[kk][m] = *(const short8*)(lds + cur * 16384 + row * 128 +
                                            (((kk * 4 + kg) ^ (row & 7)) * 16));
            }
#pragma unroll
        for (int kk = 0; kk < 2; ++kk)
#pragma unroll
            for (int m = 0; m < 4; ++m)
#pragma unroll
                for (int nn = 0; nn < 2; ++nn)
                    acc[m][nn] = __builtin_amdgcn_mfma_f32_16x16x32_bf16(a[kk][m], b[kk][nn], acc[m][nn], 0, 0, 0);
        __syncthreads();
    }

#pragma unroll
    for (int m = 0; m < 4; ++m) {
        int r4 = row0 + wr * 64 + m * 16 + kg * 4;
#pragma unroll
        for (int j = 0; j < 4; ++j) {
            int grow = r4 + j;
            if (grow < M) {
                float dv = dinv[grow];
#pragma unroll
                for (int nn = 0; nn < 2; ++nn)
                    Hout[(size_t)grow * H2P + colb + nn * 16 + lr] =
                        (unsigned short)f2bf(acc[m][nn][j] * dv);
            }
        }
    }
}

// ---------------- CSR gather layer 1 (CH=48, bf16 out) ---------------------
template <int CH, int OUTBF>
__global__ __launch_bounds__(256) void k_gat(const uint2* __restrict__ H,
                                             const float* __restrict__ dinv,
                                             const int* __restrict__ rp,
                                             const int* __restrict__ csr,
                                             const float* __restrict__ bias,
                                             void* __restrict__ outv, int n) {
    int wv = threadIdx.x >> 6, l = threadIdx.x & 63;
    int i = blockIdx.x * 4 + wv;
    if (i >= n) return;
    bool act = l < CH;
    int c = act ? l : 0;
    const uint2* Hr = H + c;

    float a0, a1, a2, a3;
    {
        uint2 v = Hr[(size_t)i * CH];
        a0 = BLO(v.x); a1 = BHI(v.x); a2 = BLO(v.y); a3 = BHI(v.y);
    }
    float p0 = 0.f, p1 = 0.f, p2 = 0.f, p3 = 0.f;

    int e0 = rp[i], e1 = rp[i + 1];
    int e = e0;
    for (; e + 1 < e1; e += 2) {
        int s0 = csr[e], s1 = csr[e + 1];
        uint2 va = Hr[(size_t)s0 * CH];
        uint2 vb = Hr[(size_t)s1 * CH];
        a0 += BLO(va.x); a1 += BHI(va.x); a2 += BLO(va.y); a3 += BHI(va.y);
        p0 += BLO(vb.x); p1 += BHI(vb.x); p2 += BLO(vb.y); p3 += BHI(vb.y);
    }
    if (e < e1) {
        int s0 = csr[e];
        uint2 va = Hr[(size_t)s0 * CH];
        a0 += BLO(va.x); a1 += BHI(va.x); a2 += BLO(va.y); a3 += BHI(va.y);
    }
    a0 += p0; a1 += p1; a2 += p2; a3 += p3;

    float di = dinv[i];
    float4 bb = *(const float4*)(bias + 4 * c);
    float o0 = fmaf(di, a0, bb.x);
    float o1 = fmaf(di, a1, bb.y);
    float o2 = fmaf(di, a2, bb.z);
    float o3 = fmaf(di, a3, bb.w);
    o0 = o0 >= 0.f ? o0 : 0.01f * o0;
    o1 = o1 >= 0.f ? o1 : 0.01f * o1;
    o2 = o2 >= 0.f ? o2 : 0.01f * o2;
    o3 = o3 >= 0.f ? o3 : 0.01f * o3;
    if (act) {
        if (OUTBF) {
            uint2 r;
            r.x = (f2bf(o1) << 16) | f2bf(o0);
            r.y = (f2bf(o3) << 16) | f2bf(o2);
            ((uint2*)outv)[(size_t)i * CH + c] = r;
        } else {
            ((float4*)outv)[(size_t)i * CH + c] = make_float4(o0, o1, o2, o3);
        }
    }
}

// ---------------- CSR gather layer 2 (CH=32, 2 nodes/wave, fp32 out) -------
__global__ __launch_bounds__(256) void k_gat2(const uint2* __restrict__ H,
                                              const float* __restrict__ dinv,
                                              const int* __restrict__ rp,
                                              const int* __restrict__ csr,
                                              const float* __restrict__ bias,
                                              float4* __restrict__ out, int n) {
    int wv = threadIdx.x >> 6, l = threadIdx.x & 63;
    int half = l >> 5, c = l & 31;
    int i = blockIdx.x * 8 + wv * 2 + half;
    if (i >= n) return;
    const uint2* Hr = H + c;

    float a0, a1, a2, a3;
    {
        uint2 v = Hr[(size_t)i * 32];
        a0 = BLO(v.x); a1 = BHI(v.x); a2 = BLO(v.y); a3 = BHI(v.y);
    }
    float p0 = 0.f, p1 = 0.f, p2 = 0.f, p3 = 0.f;

    int e0 = rp[i], e1 = rp[i + 1];
    int e = e0;
    for (; e + 1 < e1; e += 2) {
        int s0 = csr[e], s1 = csr[e + 1];
        uint2 va = Hr[(size_t)s0 * 32];
        uint2 vb = Hr[(size_t)s1 * 32];
        a0 += BLO(va.x); a1 += BHI(va.x); a2 += BLO(va.y); a3 += BHI(va.y);
        p0 += BLO(vb.x); p1 += BHI(vb.x); p2 += BLO(vb.y); p3 += BHI(vb.y);
    }
    if (e < e1) {
        int s0 = csr[e];
        uint2 va = Hr[(size_t)s0 * 32];
        a0 += BLO(va.x); a1 += BHI(va.x); a2 += BLO(va.y); a3 += BHI(va.y);
    }
    a0 += p0; a1 += p1; a2 += p2; a3 += p3;

    float di = dinv[i];
    float4 bb = *(const float4*)(bias + 4 * c);
    float o0 = fmaf(di, a0, bb.x);
    float o1 = fmaf(di, a1, bb.y);
    float o2 = fmaf(di, a2, bb.z);
    float o3 = fmaf(di, a3, bb.w);
    o0 = o0 >= 0.f ? o0 : 0.01f * o0;
    o1 = o1 >= 0.f ? o1 : 0.01f * o1;
    o2 = o2 >= 0.f ? o2 : 0.01f * o2;
    o3 = o3 >= 0.f ? o3 : 0.01f * o3;
    out[(size_t)i * 32 + c] = make_float4(o0, o1, o2, o3);
}

// ---------------- final layer + log_softmax (fp32) -------------------------
__global__ __launch_bounds__(256) void k_out(const float* __restrict__ H,
                                             const float* __restrict__ W3p,
                                             const float* __restrict__ b3,
                                             float* __restrict__ out, int M) {
    __shared__ float w[H2P * NCP];
    int t = threadIdx.x;
    {
        const float4* src = (const float4*)W3p;
        float4* dst = (float4*)w;
#pragma unroll
        for (int j = 0; j < (H2P * NCP / 4) / 256; ++j) dst[t + 256 * j] = src[t + 256 * j];
    }
    __syncthreads();
    int wave = t >> 6, lane = t & 63;
    float bias = (lane < NC) ? b3[lane] : -__builtin_inff();
    for (int rr = blockIdx.x * 4 + wave; rr < M; rr += gridDim.x * 4) {
        const float4* hr = (const float4*)(H + (size_t)rr * H2P);
        float acc = 0.f;
#pragma unroll
        for (int kq = 0; kq < H2P / 4; ++kq) {
            float4 hv = hr[kq];
            acc += hv.x * w[(kq * 4 + 0) * NCP + lane];
            acc += hv.y * w[(kq * 4 + 1) * NCP + lane];
            acc += hv.z * w[(kq * 4 + 2) * NCP + lane];
            acc += hv.w * w[(kq * 4 + 3) * NCP + lane];
        }
        float logit = acc + bias;
        float m = logit;
#pragma unroll
        for (int d = 1; d < 64; d <<= 1) m = fmaxf(m, __shfl_xor(m, d));
        float p = expf(logit - m);
        float ssum = p;
#pragma unroll
        for (int d = 1; d < 64; d <<= 1) ssum += __shfl_xor(ssum, d);
        float res = logit - m - logf(ssum);
        if (lane < NC) out[(size_t)rr * NC + lane] = res;
    }
}

// ---------------------------------------------------------------------------
extern "C" void kernel_launch(void* const* d_in, const int* in_sizes, int n_in,
                              void* d_out, int out_size, void* d_ws, size_t ws_size,
                              hipStream_t stream) {
    const float* x  = (const float*)d_in[0];
    const int*   ei = (const int*)d_in[1];
    const float* W1 = (const float*)d_in[2];
    const float* b1 = (const float*)d_in[3];
    const float* W2 = (const float*)d_in[4];
    const float* b2 = (const float*)d_in[5];
    const float* W3 = (const float*)d_in[6];
    const float* b3 = (const float*)d_in[7];
    float* outp = (float*)d_out;

    int n = in_sizes[0] / F_IN;   // 100000
    int E = in_sizes[1] / 2;      // 1600000

    char* p = (char*)d_ws;
    auto alloc = [&](size_t bytes) -> char* {
        char* r = p;
        p += (bytes + 511) & ~(size_t)511;
        return r;
    };
    int*            flag   = (int*)alloc(4);
    int*            deg    = (int*)alloc((size_t)n * 4);
    float*          dinv   = (float*)alloc((size_t)n * 4);
    int*            rp     = (int*)alloc((size_t)(n + 1) * 4);
    int*            cursor = (int*)alloc((size_t)n * 4);
    int*            bsum   = (int*)alloc(4096);
    int*            csr    = (int*)alloc((size_t)E * 4);
    unsigned short* W1s    = (unsigned short*)alloc((size_t)F_IN * H1P * 2);
    unsigned short* W2s    = (unsigned short*)alloc((size_t)H1P * H2P * 2);
    float*          W3p    = (float*)alloc((size_t)H2P * NCP * 4);
    float*          b1p    = (float*)alloc(H1P * 4);
    float*          b2p    = (float*)alloc(H2P * 4);
    unsigned short* h1     = (unsigned short*)alloc((size_t)n * H1P * 2);
    unsigned short* h1agg  = (unsigned short*)alloc((size_t)n * H1P * 2);
    unsigned short* h2     = (unsigned short*)alloc((size_t)n * H2P * 2);
    float*          h2agg  = (float*)alloc((size_t)n * H2P * 4);

    hipMemsetAsync(flag, 1, 4, stream);
    hipMemsetAsync(deg, 0, (size_t)n * 4, stream);

    k_detect<<<16, 256, 0, stream>>>(ei, flag);

    int eb = (E + 255) / 256;
    k_hist<<<eb, 256, 0, stream>>>(ei, E, flag, deg);
    k_dinv<<<(n + 255) / 256, 256, 0, stream>>>(deg, dinv, n);

    int nb = (n + 1023) / 1024;
    k_scan1<<<nb, 256, 0, stream>>>(deg, rp, bsum, n);
    k_scan2<<<1, 128, 0, stream>>>(bsum, nb);
    k_scan3<<<(n + 1 + 255) / 256, 256, 0, stream>>>(bsum, rp, cursor, n, E);
    k_fill<<<eb, 256, 0, stream>>>(ei, E, flag, cursor, csr);

    k_prepw<<<(F_IN * H1P + 255) / 256, 256, 0, stream>>>(W1, W1s, F_IN, H1V, F_IN, H1P);
    k_prepw<<<(H1P * H2P + 255) / 256, 256, 0, stream>>>(W2, W2s, H1V, H2V, H1P, H2P);
    k_pad<<<(H2P * NCP + 255) / 256, 256, 0, stream>>>(W3, W3p, H2V, NC, NCP, H2P * NCP);
    k_pad<<<1, 256, 0, stream>>>(b1, b1p, 1, H1V, H1P, H1P);
    k_pad<<<1, 256, 0, stream>>>(b2, b2p, 1, H2V, H2P, H2P);

    int gb = (n + 127) / 128;
    // layer 1
    k_gemm1<<<gb, 512, 0, stream>>>(x, (const short8*)W1s, dinv, h1, n);
    k_gat<H1P / 4, 1><<<(n + 3) / 4, 256, 0, stream>>>((const uint2*)h1, dinv, rp, csr, b1p, h1agg, n);
    // layer 2
    k_gemm2<<<gb, 512, 0, stream>>>(h1agg, (const short8*)W2s, dinv, h2, n);
    k_gat2<<<(n + 7) / 8, 256, 0, stream>>>((const uint2*)h2, dinv, rp, csr, b2p, (float4*)h2agg, n);
    // output layer + log_softmax
    k_out<<<4096, 256, 0, stream>>>(h2agg, W3p, b3, outp, n);
}

// Round 4
// 498.794 us; speedup vs baseline: 2.1431x; 1.2034x over previous
//
#include <hip/hip_runtime.h>
#include <math.h>

typedef __attribute__((ext_vector_type(8))) short short8;
typedef __attribute__((ext_vector_type(4))) float f32x4;

static constexpr int F_IN = 512;
static constexpr int H1V = 180, H1P = 192;
static constexpr int H2V = 120, H2P = 128;
static constexpr int NC  = 40,  NCP = 64;

__device__ inline unsigned f2bf(float f) {
    unsigned u = __float_as_uint(f);
    return (u + 0x7fffu + ((u >> 16) & 1u)) >> 16;   // RNE
}
__device__ inline unsigned cvtpk(float lo, float hi) {
    unsigned r;
    asm("v_cvt_pk_bf16_f32 %0, %1, %2" : "=v"(r) : "v"(lo), "v"(hi));
    return r;
}
#define BLO(u) __uint_as_float((u) << 16)
#define BHI(u) __uint_as_float((u) & 0xffff0000u)

__device__ inline void gload_lds16(const void* gsrc, void* ldst) {
    __builtin_amdgcn_global_load_lds(
        (const __attribute__((address_space(1))) void*)gsrc,
        (__attribute__((address_space(3))) void*)ldst, 16, 0, 0);
}

// ---------------- edge dtype detection (int32 vs int64 layout) -------------
__global__ void k_detect(const int* __restrict__ ei, int* __restrict__ flag) {
    int i = blockIdx.x * 256 + threadIdx.x;
    if (ei[2 * i + 1] != 0) flag[0] = 0;
}

// ---------------- degree histogram + per-edge rank -------------------------
__global__ void k_hist(const int* __restrict__ ei, int E, const int* __restrict__ flag,
                       int* __restrict__ deg, int* __restrict__ rank) {
    int e = blockIdx.x * 256 + threadIdx.x;
    if (e >= E) return;
    int d = flag[0] ? ei[2 * E + 2 * e] : ei[E + e];
    rank[e] = atomicAdd(&deg[d], 1);
}

__global__ void k_dinv(const int* __restrict__ deg, float* __restrict__ dinv, int n) {
    int i = blockIdx.x * 256 + threadIdx.x;
    if (i < n) dinv[i] = rsqrtf((float)(deg[i] + 1));
}

// ---------------- exclusive scan (3-kernel) --------------------------------
__global__ void k_scan1(const int* __restrict__ deg, int* __restrict__ rp,
                        int* __restrict__ bsum, int n) {
    __shared__ int s[256];
    int t = threadIdx.x;
    int base = blockIdx.x * 1024 + t * 4;
    int v0 = (base + 0 < n) ? deg[base + 0] : 0;
    int v1 = (base + 1 < n) ? deg[base + 1] : 0;
    int v2 = (base + 2 < n) ? deg[base + 2] : 0;
    int v3 = (base + 3 < n) ? deg[base + 3] : 0;
    int sum = v0 + v1 + v2 + v3;
    s[t] = sum;
    __syncthreads();
    for (int off = 1; off < 256; off <<= 1) {
        int x = (t >= off) ? s[t - off] : 0;
        __syncthreads();
        s[t] += x;
        __syncthreads();
    }
    int run = s[t] - sum;
    if (t == 255) bsum[blockIdx.x] = s[255];
    if (base + 0 < n) rp[base + 0] = run; run += v0;
    if (base + 1 < n) rp[base + 1] = run; run += v1;
    if (base + 2 < n) rp[base + 2] = run; run += v2;
    if (base + 3 < n) rp[base + 3] = run;
}

__global__ void k_scan2(int* __restrict__ bsum, int nb) {
    __shared__ int s[128];
    int t = threadIdx.x;
    int v = (t < nb) ? bsum[t] : 0;
    s[t] = v;
    __syncthreads();
    for (int off = 1; off < 128; off <<= 1) {
        int x = (t >= off) ? s[t - off] : 0;
        __syncthreads();
        s[t] += x;
        __syncthreads();
    }
    if (t < nb) bsum[t] = s[t] - v;
}

__global__ void k_scan3(const int* __restrict__ bsum, int* __restrict__ rp,
                        int n, int E) {
    int i = blockIdx.x * 256 + threadIdx.x;
    if (i < n) {
        rp[i] = rp[i] + bsum[i >> 10];
    } else if (i == n) {
        rp[n] = E;
    }
}

// ---------------- CSR fill: atomic-free, XCD-bucketed by dst range ---------
// block b: bucket = b&7 (round-robin -> XCD affinity), edge chunk = b>>3.
// Each bucket's csr segment (~800KB) stays in one XCD's L2 -> writeback once.
__global__ __launch_bounds__(256) void k_fill(const int* __restrict__ ei, int E,
                                              const int* __restrict__ flag,
                                              const int* __restrict__ rp,
                                              const int* __restrict__ rank,
                                              int* __restrict__ csr,
                                              int bw, int chunk) {
    int bkt = blockIdx.x & 7;
    int lo = bkt * bw, hi = lo + bw;
    int ch = blockIdx.x >> 3;
    int e0 = ch * chunk;
    int e1 = min(E, e0 + chunk);
    bool i64 = flag[0] != 0;
    for (int e = e0 + (int)threadIdx.x; e < e1; e += 256) {
        int d = i64 ? ei[2 * E + 2 * e] : ei[E + e];
        if (d >= lo && d < hi) {
            int s = i64 ? ei[2 * e] : ei[e];
            csr[rp[d] + rank[e]] = s;
        }
    }
}

// ---------------- fp32 zero-pad (W3, biases) -------------------------------
__global__ void k_pad(const float* __restrict__ src, float* __restrict__ dst,
                      int KS, int NS, int ND, int total) {
    int i = blockIdx.x * 256 + threadIdx.x;
    if (i >= total) return;
    int k = i / ND, nn = i % ND;
    dst[i] = (k < KS && nn < NS) ? src[k * NS + nn] : 0.0f;
}

// ---------------- bf16 MFMA B-fragment staging -----------------------------
__global__ void k_prepw(const float* __restrict__ src, unsigned short* __restrict__ dst,
                        int KS, int NS, int KD, int ND) {
    int i = blockIdx.x * 256 + threadIdx.x;
    if (i >= KD * ND) return;
    int k = i / ND, c = i % ND;
    float v = (k < KS && c < NS) ? src[k * NS + c] : 0.0f;
    dst[(size_t)(k >> 3) * ND * 8 + c * 8 + (k & 7)] = (unsigned short)f2bf(v);
}

// ---------------- GEMM1: h1' = dinv * (x @ W1) -----------------------------
__global__ __launch_bounds__(512) void k_gemm1(const float* __restrict__ X,
                                               const short8* __restrict__ Bs,
                                               const float* __restrict__ dinv,
                                               unsigned short* __restrict__ Hout,
                                               int M) {
    __shared__ float ldsf[8192];   // 2 x 16 KB
    char* lds = (char*)ldsf;
    int t = threadIdx.x;
    int w = t >> 6, l = t & 63;
    int lr = l & 15, kg = l >> 4;
    int wr = w >> 2, wc = w & 3;
    int row0 = blockIdx.x * 128;
    int colb = wc * 48;

    f32x4 acc[4][3];
#pragma unroll
    for (int m = 0; m < 4; ++m)
#pragma unroll
        for (int nn = 0; nn < 3; ++nn) acc[m][nn] = (f32x4){0.f, 0.f, 0.f, 0.f};

    auto stage = [&](int kb, int buf) {
#pragma unroll
        for (int j = 0; j < 2; ++j) {
            int o = j * 8192 + t * 16;
            int row = o >> 7;
            int col4 = ((o >> 4) & 7) ^ (row & 7);
            int rowg = row0 + row;
            if (rowg >= M) rowg = M - 1;
            gload_lds16(X + (size_t)rowg * F_IN + kb + col4 * 4,
                        lds + buf * 16384 + j * 8192 + w * 1024);
        }
    };

    stage(0, 0);
    __syncthreads();

    for (int ts = 0; ts < 16; ++ts) {
        int cur = ts & 1;
        if (ts < 15) stage((ts + 1) * 32, cur ^ 1);
        short8 b[3];
#pragma unroll
        for (int nn = 0; nn < 3; ++nn)
            b[nn] = Bs[(size_t)(ts * 4 + kg) * H1P + colb + nn * 16 + lr];
        short8 a[4];
#pragma unroll
        for (int m = 0; m < 4; ++m) {
            int row = wr * 64 + m * 16 + lr;
            char* base = lds + cur * 16384 + row * 128;
            float4 v0 = *(const float4*)(base + (((2 * kg + 0) ^ (row & 7)) * 16));
            float4 v1 = *(const float4*)(base + (((2 * kg + 1) ^ (row & 7)) * 16));
            union { unsigned u[4]; short8 s; } cu;
            cu.u[0] = cvtpk(v0.x, v0.y);
            cu.u[1] = cvtpk(v0.z, v0.w);
            cu.u[2] = cvtpk(v1.x, v1.y);
            cu.u[3] = cvtpk(v1.z, v1.w);
            a[m] = cu.s;
        }
#pragma unroll
        for (int m = 0; m < 4; ++m)
#pragma unroll
            for (int nn = 0; nn < 3; ++nn)
                acc[m][nn] = __builtin_amdgcn_mfma_f32_16x16x32_bf16(a[m], b[nn], acc[m][nn], 0, 0, 0);
        __syncthreads();
    }

#pragma unroll
    for (int m = 0; m < 4; ++m) {
        int r4 = row0 + wr * 64 + m * 16 + kg * 4;
#pragma unroll
        for (int j = 0; j < 4; ++j) {
            int grow = r4 + j;
            if (grow < M) {
                float dv = dinv[grow];
#pragma unroll
                for (int nn = 0; nn < 3; ++nn)
                    Hout[(size_t)grow * H1P + colb + nn * 16 + lr] =
                        (unsigned short)f2bf(acc[m][nn][j] * dv);
            }
        }
    }
}

// ---------------- GEMM2: h2' = dinv * (h1agg @ W2), bf16 in ---------------
__global__ __launch_bounds__(512) void k_gemm2(const unsigned short* __restrict__ A,
                                               const short8* __restrict__ Bs,
                                               const float* __restrict__ dinv,
                                               unsigned short* __restrict__ Hout,
                                               int M) {
    __shared__ unsigned short ldsu[16384];   // 2 x 16 KB
    char* lds = (char*)ldsu;
    int t = threadIdx.x;
    int w = t >> 6, l = t & 63;
    int lr = l & 15, kg = l >> 4;
    int wr = w >> 2, wc = w & 3;
    int row0 = blockIdx.x * 128;
    int colb = wc * 32;

    f32x4 acc[4][2];
#pragma unroll
    for (int m = 0; m < 4; ++m)
#pragma unroll
        for (int nn = 0; nn < 2; ++nn) acc[m][nn] = (f32x4){0.f, 0.f, 0.f, 0.f};

    auto stage = [&](int kb, int buf) {
#pragma unroll
        for (int j = 0; j < 2; ++j) {
            int o = j * 8192 + t * 16;
            int row = o >> 7;
            int chunk = ((o >> 4) & 7) ^ (row & 7);
            int rowg = row0 + row;
            if (rowg >= M) rowg = M - 1;
            gload_lds16(A + (size_t)rowg * H1P + kb + chunk * 8,
                        lds + buf * 16384 + j * 8192 + w * 1024);
        }
    };

    stage(0, 0);
    __syncthreads();

    for (int ts = 0; ts < 3; ++ts) {
        int cur = ts & 1;
        if (ts < 2) stage((ts + 1) * 64, cur ^ 1);
        short8 b[2][2];
#pragma unroll
        for (int kk = 0; kk < 2; ++kk)
#pragma unroll
            for (int nn = 0; nn < 2; ++nn)
                b[kk][nn] = Bs[(size_t)(ts * 8 + kk * 4 + kg) * H2P + colb + nn * 16 + lr];
        short8 a[2][4];
#pragma unroll
        for (int kk = 0; kk < 2; ++kk)
#pragma unroll
            for (int m = 0; m < 4; ++m) {
                int row = wr * 64 + m * 16 + lr;
                a[kk][m] = *(const short8*)(lds + cur * 16384 + row * 128 +
                                            (((kk * 4 + kg) ^ (row & 7)) * 16));
            }
#pragma unroll
        for (int kk = 0; kk < 2; ++kk)
#pragma unroll
            for (int m = 0; m < 4; ++m)
#pragma unroll
                for (int nn = 0; nn < 2; ++nn)
                    acc[m][nn] = __builtin_amdgcn_mfma_f32_16x16x32_bf16(a[kk][m], b[kk][nn], acc[m][nn], 0, 0, 0);
        __syncthreads();
    }

#pragma unroll
    for (int m = 0; m < 4; ++m) {
        int r4 = row0 + wr * 64 + m * 16 + kg * 4;
#pragma unroll
        for (int j = 0; j < 4; ++j) {
            int grow = r4 + j;
            if (grow < M) {
                float dv = dinv[grow];
#pragma unroll
                for (int nn = 0; nn < 2; ++nn)
                    Hout[(size_t)grow * H2P + colb + nn * 16 + lr] =
                        (unsigned short)f2bf(acc[m][nn][j] * dv);
            }
        }
    }
}

// ---------------- CSR gather layer 1 (CH=48, bf16 out, 4-deep ILP) ---------
template <int CH, int OUTBF>
__global__ __launch_bounds__(256) void k_gat(const uint2* __restrict__ H,
                                             const float* __restrict__ dinv,
                                             const int* __restrict__ rp,
                                             const int* __restrict__ csr,
                                             const float* __restrict__ bias,
                                             void* __restrict__ outv, int n) {
    int wv = threadIdx.x >> 6, l = threadIdx.x & 63;
    int i = blockIdx.x * 4 + wv;
    if (i >= n) return;
    bool act = l < CH;
    int c = act ? l : 0;
    const uint2* Hr = H + c;

    float a0, a1, a2, a3;
    {
        uint2 v = Hr[(size_t)i * CH];
        a0 = BLO(v.x); a1 = BHI(v.x); a2 = BLO(v.y); a3 = BHI(v.y);
    }
    float p0 = 0.f, p1 = 0.f, p2 = 0.f, p3 = 0.f;

    int e0 = rp[i], e1 = rp[i + 1];
    int e = e0;
    for (; e + 3 < e1; e += 4) {
        int s0 = csr[e], s1 = csr[e + 1], s2 = csr[e + 2], s3 = csr[e + 3];
        uint2 va = Hr[(size_t)s0 * CH];
        uint2 vb = Hr[(size_t)s1 * CH];
        uint2 vc = Hr[(size_t)s2 * CH];
        uint2 vd = Hr[(size_t)s3 * CH];
        a0 += BLO(va.x); a1 += BHI(va.x); a2 += BLO(va.y); a3 += BHI(va.y);
        p0 += BLO(vb.x); p1 += BHI(vb.x); p2 += BLO(vb.y); p3 += BHI(vb.y);
        a0 += BLO(vc.x); a1 += BHI(vc.x); a2 += BLO(vc.y); a3 += BHI(vc.y);
        p0 += BLO(vd.x); p1 += BHI(vd.x); p2 += BLO(vd.y); p3 += BHI(vd.y);
    }
    for (; e < e1; ++e) {
        int s0 = csr[e];
        uint2 va = Hr[(size_t)s0 * CH];
        a0 += BLO(va.x); a1 += BHI(va.x); a2 += BLO(va.y); a3 += BHI(va.y);
    }
    a0 += p0; a1 += p1; a2 += p2; a3 += p3;

    float di = dinv[i];
    float4 bb = *(const float4*)(bias + 4 * c);
    float o0 = fmaf(di, a0, bb.x);
    float o1 = fmaf(di, a1, bb.y);
    float o2 = fmaf(di, a2, bb.z);
    float o3 = fmaf(di, a3, bb.w);
    o0 = o0 >= 0.f ? o0 : 0.01f * o0;
    o1 = o1 >= 0.f ? o1 : 0.01f * o1;
    o2 = o2 >= 0.f ? o2 : 0.01f * o2;
    o3 = o3 >= 0.f ? o3 : 0.01f * o3;
    if (act) {
        if (OUTBF) {
            uint2 r;
            r.x = (f2bf(o1) << 16) | f2bf(o0);
            r.y = (f2bf(o3) << 16) | f2bf(o2);
            ((uint2*)outv)[(size_t)i * CH + c] = r;
        } else {
            ((float4*)outv)[(size_t)i * CH + c] = make_float4(o0, o1, o2, o3);
        }
    }
}

// ---------------- CSR gather layer 2 (CH=32, 2 nodes/wave, 4-deep ILP) -----
__global__ __launch_bounds__(256) void k_gat2(const uint2* __restrict__ H,
                                              const float* __restrict__ dinv,
                                              const int* __restrict__ rp,
                                              const int* __restrict__ csr,
                                              const float* __restrict__ bias,
                                              float4* __restrict__ out, int n) {
    int wv = threadIdx.x >> 6, l = threadIdx.x & 63;
    int half = l >> 5, c = l & 31;
    int i = blockIdx.x * 8 + wv * 2 + half;
    if (i >= n) return;
    const uint2* Hr = H + c;

    float a0, a1, a2, a3;
    {
        uint2 v = Hr[(size_t)i * 32];
        a0 = BLO(v.x); a1 = BHI(v.x); a2 = BLO(v.y); a3 = BHI(v.y);
    }
    float p0 = 0.f, p1 = 0.f, p2 = 0.f, p3 = 0.f;

    int e0 = rp[i], e1 = rp[i + 1];
    int e = e0;
    for (; e + 3 < e1; e += 4) {
        int s0 = csr[e], s1 = csr[e + 1], s2 = csr[e + 2], s3 = csr[e + 3];
        uint2 va = Hr[(size_t)s0 * 32];
        uint2 vb = Hr[(size_t)s1 * 32];
        uint2 vc = Hr[(size_t)s2 * 32];
        uint2 vd = Hr[(size_t)s3 * 32];
        a0 += BLO(va.x); a1 += BHI(va.x); a2 += BLO(va.y); a3 += BHI(va.y);
        p0 += BLO(vb.x); p1 += BHI(vb.x); p2 += BLO(vb.y); p3 += BHI(vb.y);
        a0 += BLO(vc.x); a1 += BHI(vc.x); a2 += BLO(vc.y); a3 += BHI(vc.y);
        p0 += BLO(vd.x); p1 += BHI(vd.x); p2 += BLO(vd.y); p3 += BHI(vd.y);
    }
    for (; e < e1; ++e) {
        int s0 = csr[e];
        uint2 va = Hr[(size_t)s0 * 32];
        a0 += BLO(va.x); a1 += BHI(va.x); a2 += BLO(va.y); a3 += BHI(va.y);
    }
    a0 += p0; a1 += p1; a2 += p2; a3 += p3;

    float di = dinv[i];
    float4 bb = *(const float4*)(bias + 4 * c);
    float o0 = fmaf(di, a0, bb.x);
    float o1 = fmaf(di, a1, bb.y);
    float o2 = fmaf(di, a2, bb.z);
    float o3 = fmaf(di, a3, bb.w);
    o0 = o0 >= 0.f ? o0 : 0.01f * o0;
    o1 = o1 >= 0.f ? o1 : 0.01f * o1;
    o2 = o2 >= 0.f ? o2 : 0.01f * o2;
    o3 = o3 >= 0.f ? o3 : 0.01f * o3;
    out[(size_t)i * 32 + c] = make_float4(o0, o1, o2, o3);
}

// ---------------- final layer + log_softmax (fp32) -------------------------
__global__ __launch_bounds__(256) void k_out(const float* __restrict__ H,
                                             const float* __restrict__ W3p,
                                             const float* __restrict__ b3,
                                             float* __restrict__ out, int M) {
    __shared__ float w[H2P * NCP];
    int t = threadIdx.x;
    {
        const float4* src = (const float4*)W3p;
        float4* dst = (float4*)w;
#pragma unroll
        for (int j = 0; j < (H2P * NCP / 4) / 256; ++j) dst[t + 256 * j] = src[t + 256 * j];
    }
    __syncthreads();
    int wave = t >> 6, lane = t & 63;
    float bias = (lane < NC) ? b3[lane] : -__builtin_inff();
    for (int rr = blockIdx.x * 4 + wave; rr < M; rr += gridDim.x * 4) {
        const float4* hr = (const float4*)(H + (size_t)rr * H2P);
        float acc = 0.f;
#pragma unroll
        for (int kq = 0; kq < H2P / 4; ++kq) {
            float4 hv = hr[kq];
            acc += hv.x * w[(kq * 4 + 0) * NCP + lane];
            acc += hv.y * w[(kq * 4 + 1) * NCP + lane];
            acc += hv.z * w[(kq * 4 + 2) * NCP + lane];
            acc += hv.w * w[(kq * 4 + 3) * NCP + lane];
        }
        float logit = acc + bias;
        float m = logit;
#pragma unroll
        for (int d = 1; d < 64; d <<= 1) m = fmaxf(m, __shfl_xor(m, d));
        float p = expf(logit - m);
        float ssum = p;
#pragma unroll
        for (int d = 1; d < 64; d <<= 1) ssum += __shfl_xor(ssum, d);
        float res = logit - m - logf(ssum);
        if (lane < NC) out[(size_t)rr * NC + lane] = res;
    }
}

// ---------------------------------------------------------------------------
extern "C" void kernel_launch(void* const* d_in, const int* in_sizes, int n_in,
                              void* d_out, int out_size, void* d_ws, size_t ws_size,
                              hipStream_t stream) {
    const float* x  = (const float*)d_in[0];
    const int*   ei = (const int*)d_in[1];
    const float* W1 = (const float*)d_in[2];
    const float* b1 = (const float*)d_in[3];
    const float* W2 = (const float*)d_in[4];
    const float* b2 = (const float*)d_in[5];
    const float* W3 = (const float*)d_in[6];
    const float* b3 = (const float*)d_in[7];
    float* outp = (float*)d_out;

    int n = in_sizes[0] / F_IN;   // 100000
    int E = in_sizes[1] / 2;      // 1600000

    char* p = (char*)d_ws;
    auto alloc = [&](size_t bytes) -> char* {
        char* r = p;
        p += (bytes + 511) & ~(size_t)511;
        return r;
    };
    int*            flag   = (int*)alloc(4);
    int*            deg    = (int*)alloc((size_t)n * 4);
    float*          dinv   = (float*)alloc((size_t)n * 4);
    int*            rp     = (int*)alloc((size_t)(n + 1) * 4);
    int*            bsum   = (int*)alloc(4096);
    int*            rank   = (int*)alloc((size_t)E * 4);
    int*            csr    = (int*)alloc((size_t)E * 4);
    unsigned short* W1s    = (unsigned short*)alloc((size_t)F_IN * H1P * 2);
    unsigned short* W2s    = (unsigned short*)alloc((size_t)H1P * H2P * 2);
    float*          W3p    = (float*)alloc((size_t)H2P * NCP * 4);
    float*          b1p    = (float*)alloc(H1P * 4);
    float*          b2p    = (float*)alloc(H2P * 4);
    unsigned short* h1     = (unsigned short*)alloc((size_t)n * H1P * 2);
    unsigned short* h1agg  = (unsigned short*)alloc((size_t)n * H1P * 2);
    unsigned short* h2     = (unsigned short*)alloc((size_t)n * H2P * 2);
    float*          h2agg  = (float*)alloc((size_t)n * H2P * 4);

    hipMemsetAsync(flag, 1, 4, stream);
    hipMemsetAsync(deg, 0, (size_t)n * 4, stream);

    k_detect<<<16, 256, 0, stream>>>(ei, flag);

    int eb = (E + 255) / 256;
    k_hist<<<eb, 256, 0, stream>>>(ei, E, flag, deg, rank);
    k_dinv<<<(n + 255) / 256, 256, 0, stream>>>(deg, dinv, n);

    int nb = (n + 1023) / 1024;
    k_scan1<<<nb, 256, 0, stream>>>(deg, rp, bsum, n);
    k_scan2<<<1, 128, 0, stream>>>(bsum, nb);
    k_scan3<<<(n + 1 + 255) / 256, 256, 0, stream>>>(bsum, rp, n, E);

    // bucketed atomic-free CSR fill: 256 chunks x 8 buckets
    int bw = (n + 7) / 8;                  // 12500
    int nch = 256;
    int chunk = (E + nch - 1) / nch;       // 6250
    k_fill<<<nch * 8, 256, 0, stream>>>(ei, E, flag, rp, rank, csr, bw, chunk);

    k_prepw<<<(F_IN * H1P + 255) / 256, 256, 0, stream>>>(W1, W1s, F_IN, H1V, F_IN, H1P);
    k_prepw<<<(H1P * H2P + 255) / 256, 256, 0, stream>>>(W2, W2s, H1V, H2V, H1P, H2P);
    k_pad<<<(H2P * NCP + 255) / 256, 256, 0, stream>>>(W3, W3p, H2V, NC, NCP, H2P * NCP);
    k_pad<<<1, 256, 0, stream>>>(b1, b1p, 1, H1V, H1P, H1P);
    k_pad<<<1, 256, 0, stream>>>(b2, b2p, 1, H2V, H2P, H2P);

    int gb = (n + 127) / 128;
    // layer 1
    k_gemm1<<<gb, 512, 0, stream>>>(x, (const short8*)W1s, dinv, h1, n);
    k_gat<H1P / 4, 1><<<(n + 3) / 4, 256, 0, stream>>>((const uint2*)h1, dinv, rp, csr, b1p, h1agg, n);
    // layer 2
    k_gemm2<<<gb, 512, 0, stream>>>(h1agg, (const short8*)W2s, dinv, h2, n);
    k_gat2<<<(n + 7) / 8, 256, 0, stream>>>((const uint2*)h2, dinv, rp, csr, b2p, (float4*)h2agg, n);
    // output layer + log_softmax
    k_out<<<4096, 256, 0, stream>>>(h2agg, W3p, b3, outp, n);
}

// Round 5
// 395.204 us; speedup vs baseline: 2.7048x; 1.2621x over previous
//
#include <hip/hip_runtime.h>
#include <math.h>

typedef __attribute__((ext_vector_type(8))) short short8;
typedef __attribute__((ext_vector_type(4))) float f32x4;

static constexpr int F_IN = 512;
static constexpr int H1V = 180, H1P = 192;
static constexpr int H2V = 120, H2P = 128;
static constexpr int NC  = 40,  NCP = 64;

__device__ inline unsigned f2bf(float f) {
    unsigned u = __float_as_uint(f);
    return (u + 0x7fffu + ((u >> 16) & 1u)) >> 16;   // RNE
}
__device__ inline unsigned cvtpk(float lo, float hi) {
    unsigned r;
    asm("v_cvt_pk_bf16_f32 %0, %1, %2" : "=v"(r) : "v"(lo), "v"(hi));
    return r;
}
#define BLO(u) __uint_as_float((u) << 16)
#define BHI(u) __uint_as_float((u) & 0xffff0000u)

__device__ inline void gload_lds16(const void* gsrc, void* ldst) {
    __builtin_amdgcn_global_load_lds(
        (const __attribute__((address_space(1))) void*)gsrc,
        (__attribute__((address_space(3))) void*)ldst, 16, 0, 0);
}

// ---------------- edge dtype detection (int32 vs int64 layout) -------------
__global__ void k_detect(const int* __restrict__ ei, int* __restrict__ flag) {
    int i = blockIdx.x * 256 + threadIdx.x;
    if (ei[2 * i + 1] != 0) flag[0] = 0;
}

// ---------------- degree histogram + per-edge rank -------------------------
__global__ void k_hist(const int* __restrict__ ei, int E, const int* __restrict__ flag,
                       int* __restrict__ deg, int* __restrict__ rank) {
    int e = blockIdx.x * 256 + threadIdx.x;
    if (e >= E) return;
    int d = flag[0] ? ei[2 * E + 2 * e] : ei[E + e];
    rank[e] = atomicAdd(&deg[d], 1);
}

__global__ void k_dinv(const int* __restrict__ deg, float* __restrict__ dinv, int n) {
    int i = blockIdx.x * 256 + threadIdx.x;
    if (i < n) dinv[i] = rsqrtf((float)(deg[i] + 1));
}

// ---------------- exclusive scan (3-kernel) --------------------------------
__global__ void k_scan1(const int* __restrict__ deg, int* __restrict__ rp,
                        int* __restrict__ bsum, int n) {
    __shared__ int s[256];
    int t = threadIdx.x;
    int base = blockIdx.x * 1024 + t * 4;
    int v0 = (base + 0 < n) ? deg[base + 0] : 0;
    int v1 = (base + 1 < n) ? deg[base + 1] : 0;
    int v2 = (base + 2 < n) ? deg[base + 2] : 0;
    int v3 = (base + 3 < n) ? deg[base + 3] : 0;
    int sum = v0 + v1 + v2 + v3;
    s[t] = sum;
    __syncthreads();
    for (int off = 1; off < 256; off <<= 1) {
        int x = (t >= off) ? s[t - off] : 0;
        __syncthreads();
        s[t] += x;
        __syncthreads();
    }
    int run = s[t] - sum;
    if (t == 255) bsum[blockIdx.x] = s[255];
    if (base + 0 < n) rp[base + 0] = run; run += v0;
    if (base + 1 < n) rp[base + 1] = run; run += v1;
    if (base + 2 < n) rp[base + 2] = run; run += v2;
    if (base + 3 < n) rp[base + 3] = run;
}

__global__ void k_scan2(int* __restrict__ bsum, int nb) {
    __shared__ int s[128];
    int t = threadIdx.x;
    int v = (t < nb) ? bsum[t] : 0;
    s[t] = v;
    __syncthreads();
    for (int off = 1; off < 128; off <<= 1) {
        int x = (t >= off) ? s[t - off] : 0;
        __syncthreads();
        s[t] += x;
        __syncthreads();
    }
    if (t < nb) bsum[t] = s[t] - v;
}

__global__ void k_scan3(const int* __restrict__ bsum, int* __restrict__ rp,
                        int n, int E) {
    int i = blockIdx.x * 256 + threadIdx.x;
    if (i < n) {
        rp[i] = rp[i] + bsum[i >> 10];
    } else if (i == n) {
        rp[n] = E;
    }
}

// ---------------- CSR fill: atomic-free, XCD-bucketed by dst range ---------
__global__ __launch_bounds__(256) void k_fill(const int* __restrict__ ei, int E,
                                              const int* __restrict__ flag,
                                              const int* __restrict__ rp,
                                              const int* __restrict__ rank,
                                              int* __restrict__ csr,
                                              int bw, int chunk) {
    int bkt = blockIdx.x & 7;
    int lo = bkt * bw, hi = lo + bw;
    int ch = blockIdx.x >> 3;
    int e0 = ch * chunk;
    int e1 = min(E, e0 + chunk);
    bool i64 = flag[0] != 0;
    for (int e = e0 + (int)threadIdx.x; e < e1; e += 256) {
        int d = i64 ? ei[2 * E + 2 * e] : ei[E + e];
        if (d >= lo && d < hi) {
            int s = i64 ? ei[2 * e] : ei[e];
            csr[rp[d] + rank[e]] = s;
        }
    }
}

// ---------------- fp32 zero-pad (biases) -----------------------------------
__global__ void k_pad(const float* __restrict__ src, float* __restrict__ dst,
                      int KS, int NS, int ND, int total) {
    int i = blockIdx.x * 256 + threadIdx.x;
    if (i >= total) return;
    int k = i / ND, nn = i % ND;
    dst[i] = (k < KS && nn < NS) ? src[k * NS + nn] : 0.0f;
}

// b3 pad with -1e30 so softmax ignores pad classes
__global__ void k_padneg(const float* __restrict__ src, float* __restrict__ dst,
                         int NS, int ND) {
    int i = threadIdx.x;
    if (i < ND) dst[i] = (i < NS) ? src[i] : -1e30f;
}

// ---------------- bf16 MFMA B-fragment staging -----------------------------
__global__ void k_prepw(const float* __restrict__ src, unsigned short* __restrict__ dst,
                        int KS, int NS, int KD, int ND) {
    int i = blockIdx.x * 256 + threadIdx.x;
    if (i >= KD * ND) return;
    int k = i / ND, c = i % ND;
    float v = (k < KS && c < NS) ? src[k * NS + c] : 0.0f;
    dst[(size_t)(k >> 3) * ND * 8 + c * 8 + (k & 7)] = (unsigned short)f2bf(v);
}

// ---------------- GEMM1: h1' = dinv * (x @ W1) -----------------------------
__global__ __launch_bounds__(512) void k_gemm1(const float* __restrict__ X,
                                               const short8* __restrict__ Bs,
                                               const float* __restrict__ dinv,
                                               unsigned short* __restrict__ Hout,
                                               int M) {
    __shared__ float ldsf[8192];   // 2 x 16 KB
    char* lds = (char*)ldsf;
    int t = threadIdx.x;
    int w = t >> 6, l = t & 63;
    int lr = l & 15, kg = l >> 4;
    int wr = w >> 2, wc = w & 3;
    int row0 = blockIdx.x * 128;
    int colb = wc * 48;

    f32x4 acc[4][3];
#pragma unroll
    for (int m = 0; m < 4; ++m)
#pragma unroll
        for (int nn = 0; nn < 3; ++nn) acc[m][nn] = (f32x4){0.f, 0.f, 0.f, 0.f};

    auto stage = [&](int kb, int buf) {
#pragma unroll
        for (int j = 0; j < 2; ++j) {
            int o = j * 8192 + t * 16;
            int row = o >> 7;
            int col4 = ((o >> 4) & 7) ^ (row & 7);
            int rowg = row0 + row;
            if (rowg >= M) rowg = M - 1;
            gload_lds16(X + (size_t)rowg * F_IN + kb + col4 * 4,
                        lds + buf * 16384 + j * 8192 + w * 1024);
        }
    };

    stage(0, 0);
    __syncthreads();

    for (int ts = 0; ts < 16; ++ts) {
        int cur = ts & 1;
        if (ts < 15) stage((ts + 1) * 32, cur ^ 1);
        short8 b[3];
#pragma unroll
        for (int nn = 0; nn < 3; ++nn)
            b[nn] = Bs[(size_t)(ts * 4 + kg) * H1P + colb + nn * 16 + lr];
        short8 a[4];
#pragma unroll
        for (int m = 0; m < 4; ++m) {
            int row = wr * 64 + m * 16 + lr;
            char* base = lds + cur * 16384 + row * 128;
            float4 v0 = *(const float4*)(base + (((2 * kg + 0) ^ (row & 7)) * 16));
            float4 v1 = *(const float4*)(base + (((2 * kg + 1) ^ (row & 7)) * 16));
            union { unsigned u[4]; short8 s; } cu;
            cu.u[0] = cvtpk(v0.x, v0.y);
            cu.u[1] = cvtpk(v0.z, v0.w);
            cu.u[2] = cvtpk(v1.x, v1.y);
            cu.u[3] = cvtpk(v1.z, v1.w);
            a[m] = cu.s;
        }
#pragma unroll
        for (int m = 0; m < 4; ++m)
#pragma unroll
            for (int nn = 0; nn < 3; ++nn)
                acc[m][nn] = __builtin_amdgcn_mfma_f32_16x16x32_bf16(a[m], b[nn], acc[m][nn], 0, 0, 0);
        __syncthreads();
    }

#pragma unroll
    for (int m = 0; m < 4; ++m) {
        int r4 = row0 + wr * 64 + m * 16 + kg * 4;
#pragma unroll
        for (int j = 0; j < 4; ++j) {
            int grow = r4 + j;
            if (grow < M) {
                float dv = dinv[grow];
#pragma unroll
                for (int nn = 0; nn < 3; ++nn)
                    Hout[(size_t)grow * H1P + colb + nn * 16 + lr] =
                        (unsigned short)f2bf(acc[m][nn][j] * dv);
            }
        }
    }
}

// ---------------- GEMM2: h2' = dinv * (h1agg @ W2), bf16 in ---------------
__global__ __launch_bounds__(512) void k_gemm2(const unsigned short* __restrict__ A,
                                               const short8* __restrict__ Bs,
                                               const float* __restrict__ dinv,
                                               unsigned short* __restrict__ Hout,
                                               int M) {
    __shared__ unsigned short ldsu[16384];   // 2 x 16 KB
    char* lds = (char*)ldsu;
    int t = threadIdx.x;
    int w = t >> 6, l = t & 63;
    int lr = l & 15, kg = l >> 4;
    int wr = w >> 2, wc = w & 3;
    int row0 = blockIdx.x * 128;
    int colb = wc * 32;

    f32x4 acc[4][2];
#pragma unroll
    for (int m = 0; m < 4; ++m)
#pragma unroll
        for (int nn = 0; nn < 2; ++nn) acc[m][nn] = (f32x4){0.f, 0.f, 0.f, 0.f};

    auto stage = [&](int kb, int buf) {
#pragma unroll
        for (int j = 0; j < 2; ++j) {
            int o = j * 8192 + t * 16;
            int row = o >> 7;
            int chunk = ((o >> 4) & 7) ^ (row & 7);
            int rowg = row0 + row;
            if (rowg >= M) rowg = M - 1;
            gload_lds16(A + (size_t)rowg * H1P + kb + chunk * 8,
                        lds + buf * 16384 + j * 8192 + w * 1024);
        }
    };

    stage(0, 0);
    __syncthreads();

    for (int ts = 0; ts < 3; ++ts) {
        int cur = ts & 1;
        if (ts < 2) stage((ts + 1) * 64, cur ^ 1);
        short8 b[2][2];
#pragma unroll
        for (int kk = 0; kk < 2; ++kk)
#pragma unroll
            for (int nn = 0; nn < 2; ++nn)
                b[kk][nn] = Bs[(size_t)(ts * 8 + kk * 4 + kg) * H2P + colb + nn * 16 + lr];
        short8 a[2][4];
#pragma unroll
        for (int kk = 0; kk < 2; ++kk)
#pragma unroll
            for (int m = 0; m < 4; ++m) {
                int row = wr * 64 + m * 16 + lr;
                a[kk][m] = *(const short8*)(lds + cur * 16384 + row * 128 +
                                            (((kk * 4 + kg) ^ (row & 7)) * 16));
            }
#pragma unroll
        for (int kk = 0; kk < 2; ++kk)
#pragma unroll
            for (int m = 0; m < 4; ++m)
#pragma unroll
                for (int nn = 0; nn < 2; ++nn)
                    acc[m][nn] = __builtin_amdgcn_mfma_f32_16x16x32_bf16(a[kk][m], b[kk][nn], acc[m][nn], 0, 0, 0);
        __syncthreads();
    }

#pragma unroll
    for (int m = 0; m < 4; ++m) {
        int r4 = row0 + wr * 64 + m * 16 + kg * 4;
#pragma unroll
        for (int j = 0; j < 4; ++j) {
            int grow = r4 + j;
            if (grow < M) {
                float dv = dinv[grow];
#pragma unroll
                for (int nn = 0; nn < 2; ++nn)
                    Hout[(size_t)grow * H2P + colb + nn * 16 + lr] =
                        (unsigned short)f2bf(acc[m][nn][j] * dv);
            }
        }
    }
}

// ---------------- CSR gather layer 1 (CH=48, bf16 out, 4-deep ILP) ---------
template <int CH, int OUTBF>
__global__ __launch_bounds__(256) void k_gat(const uint2* __restrict__ H,
                                             const float* __restrict__ dinv,
                                             const int* __restrict__ rp,
                                             const int* __restrict__ csr,
                                             const float* __restrict__ bias,
                                             void* __restrict__ outv, int n) {
    int wv = threadIdx.x >> 6, l = threadIdx.x & 63;
    int i = blockIdx.x * 4 + wv;
    if (i >= n) return;
    bool act = l < CH;
    int c = act ? l : 0;
    const uint2* Hr = H + c;

    float a0, a1, a2, a3;
    {
        uint2 v = Hr[(size_t)i * CH];
        a0 = BLO(v.x); a1 = BHI(v.x); a2 = BLO(v.y); a3 = BHI(v.y);
    }
    float p0 = 0.f, p1 = 0.f, p2 = 0.f, p3 = 0.f;

    int e0 = rp[i], e1 = rp[i + 1];
    int e = e0;
    for (; e + 3 < e1; e += 4) {
        int s0 = csr[e], s1 = csr[e + 1], s2 = csr[e + 2], s3 = csr[e + 3];
        uint2 va = Hr[(size_t)s0 * CH];
        uint2 vb = Hr[(size_t)s1 * CH];
        uint2 vc = Hr[(size_t)s2 * CH];
        uint2 vd = Hr[(size_t)s3 * CH];
        a0 += BLO(va.x); a1 += BHI(va.x); a2 += BLO(va.y); a3 += BHI(va.y);
        p0 += BLO(vb.x); p1 += BHI(vb.x); p2 += BLO(vb.y); p3 += BHI(vb.y);
        a0 += BLO(vc.x); a1 += BHI(vc.x); a2 += BLO(vc.y); a3 += BHI(vc.y);
        p0 += BLO(vd.x); p1 += BHI(vd.x); p2 += BLO(vd.y); p3 += BHI(vd.y);
    }
    for (; e < e1; ++e) {
        int s0 = csr[e];
        uint2 va = Hr[(size_t)s0 * CH];
        a0 += BLO(va.x); a1 += BHI(va.x); a2 += BLO(va.y); a3 += BHI(va.y);
    }
    a0 += p0; a1 += p1; a2 += p2; a3 += p3;

    float di = dinv[i];
    float4 bb = *(const float4*)(bias + 4 * c);
    float o0 = fmaf(di, a0, bb.x);
    float o1 = fmaf(di, a1, bb.y);
    float o2 = fmaf(di, a2, bb.z);
    float o3 = fmaf(di, a3, bb.w);
    o0 = o0 >= 0.f ? o0 : 0.01f * o0;
    o1 = o1 >= 0.f ? o1 : 0.01f * o1;
    o2 = o2 >= 0.f ? o2 : 0.01f * o2;
    o3 = o3 >= 0.f ? o3 : 0.01f * o3;
    if (act) {
        if (OUTBF) {
            uint2 r;
            r.x = (f2bf(o1) << 16) | f2bf(o0);
            r.y = (f2bf(o3) << 16) | f2bf(o2);
            ((uint2*)outv)[(size_t)i * CH + c] = r;
        } else {
            ((float4*)outv)[(size_t)i * CH + c] = make_float4(o0, o1, o2, o3);
        }
    }
}

// ---------------- CSR gather layer 2 (CH=32, 2 nodes/wave, bf16 out) -------
__global__ __launch_bounds__(256) void k_gat2(const uint2* __restrict__ H,
                                              const float* __restrict__ dinv,
                                              const int* __restrict__ rp,
                                              const int* __restrict__ csr,
                                              const float* __restrict__ bias,
                                              uint2* __restrict__ out, int n) {
    int wv = threadIdx.x >> 6, l = threadIdx.x & 63;
    int half = l >> 5, c = l & 31;
    int i = blockIdx.x * 8 + wv * 2 + half;
    if (i >= n) return;
    const uint2* Hr = H + c;

    float a0, a1, a2, a3;
    {
        uint2 v = Hr[(size_t)i * 32];
        a0 = BLO(v.x); a1 = BHI(v.x); a2 = BLO(v.y); a3 = BHI(v.y);
    }
    float p0 = 0.f, p1 = 0.f, p2 = 0.f, p3 = 0.f;

    int e0 = rp[i], e1 = rp[i + 1];
    int e = e0;
    for (; e + 3 < e1; e += 4) {
        int s0 = csr[e], s1 = csr[e + 1], s2 = csr[e + 2], s3 = csr[e + 3];
        uint2 va = Hr[(size_t)s0 * 32];
        uint2 vb = Hr[(size_t)s1 * 32];
        uint2 vc = Hr[(size_t)s2 * 32];
        uint2 vd = Hr[(size_t)s3 * 32];
        a0 += BLO(va.x); a1 += BHI(va.x); a2 += BLO(va.y); a3 += BHI(va.y);
        p0 += BLO(vb.x); p1 += BHI(vb.x); p2 += BLO(vb.y); p3 += BHI(vb.y);
        a0 += BLO(vc.x); a1 += BHI(vc.x); a2 += BLO(vc.y); a3 += BHI(vc.y);
        p0 += BLO(vd.x); p1 += BHI(vd.x); p2 += BLO(vd.y); p3 += BHI(vd.y);
    }
    for (; e < e1; ++e) {
        int s0 = csr[e];
        uint2 va = Hr[(size_t)s0 * 32];
        a0 += BLO(va.x); a1 += BHI(va.x); a2 += BLO(va.y); a3 += BHI(va.y);
    }
    a0 += p0; a1 += p1; a2 += p2; a3 += p3;

    float di = dinv[i];
    float4 bb = *(const float4*)(bias + 4 * c);
    float o0 = fmaf(di, a0, bb.x);
    float o1 = fmaf(di, a1, bb.y);
    float o2 = fmaf(di, a2, bb.z);
    float o3 = fmaf(di, a3, bb.w);
    o0 = o0 >= 0.f ? o0 : 0.01f * o0;
    o1 = o1 >= 0.f ? o1 : 0.01f * o1;
    o2 = o2 >= 0.f ? o2 : 0.01f * o2;
    o3 = o3 >= 0.f ? o3 : 0.01f * o3;
    uint2 r;
    r.x = (f2bf(o1) << 16) | f2bf(o0);
    r.y = (f2bf(o3) << 16) | f2bf(o2);
    out[(size_t)i * 32 + c] = r;
}

// ---------------- final layer: MFMA GEMM (128->64) + fused log_softmax -----
// 64 rows/block, 4 waves x one 16x64 tile. A = bf16 h2agg direct; B = W3 frags.
// C/D: col = lane&15 (+16*frag), row = (lane>>4)*4 + reg.
__global__ __launch_bounds__(256) void k_out(const unsigned short* __restrict__ H,
                                             const short8* __restrict__ Bs,
                                             const float* __restrict__ b3p,
                                             float* __restrict__ out, int M) {
    int t = threadIdx.x;
    int w = t >> 6, l = t & 63;
    int lr = l & 15, kg = l >> 4;
    int row0 = blockIdx.x * 64 + w * 16;

    f32x4 acc[4];
#pragma unroll
    for (int f = 0; f < 4; ++f) acc[f] = (f32x4){0.f, 0.f, 0.f, 0.f};

    int rowa = row0 + lr;
    if (rowa >= M) rowa = M - 1;
    const unsigned short* arow = H + (size_t)rowa * H2P;

#pragma unroll
    for (int ks = 0; ks < 4; ++ks) {
        short8 a = *(const short8*)(arow + ks * 32 + kg * 8);
#pragma unroll
        for (int f = 0; f < 4; ++f) {
            short8 b = Bs[(size_t)(ks * 4 + kg) * NCP + f * 16 + lr];
            acc[f] = __builtin_amdgcn_mfma_f32_16x16x32_bf16(a, b, acc[f], 0, 0, 0);
        }
    }

    float bl[4];
#pragma unroll
    for (int f = 0; f < 4; ++f) bl[f] = b3p[f * 16 + lr];

#pragma unroll
    for (int j = 0; j < 4; ++j) {
        int grow = row0 + kg * 4 + j;
        float lg[4];
#pragma unroll
        for (int f = 0; f < 4; ++f) lg[f] = acc[f][j] + bl[f];
        float m = fmaxf(fmaxf(lg[0], lg[1]), fmaxf(lg[2], lg[3]));
#pragma unroll
        for (int d = 1; d < 16; d <<= 1) m = fmaxf(m, __shfl_xor(m, d));
        float s = expf(lg[0] - m) + expf(lg[1] - m) + expf(lg[2] - m) + expf(lg[3] - m);
#pragma unroll
        for (int d = 1; d < 16; d <<= 1) s += __shfl_xor(s, d);
        float lse = m + logf(s);
        if (grow < M) {
#pragma unroll
            for (int f = 0; f < 4; ++f) {
                int c = f * 16 + lr;
                if (c < NC) out[(size_t)grow * NC + c] = lg[f] - lse;
            }
        }
    }
}

// ---------------------------------------------------------------------------
extern "C" void kernel_launch(void* const* d_in, const int* in_sizes, int n_in,
                              void* d_out, int out_size, void* d_ws, size_t ws_size,
                              hipStream_t stream) {
    const float* x  = (const float*)d_in[0];
    const int*   ei = (const int*)d_in[1];
    const float* W1 = (const float*)d_in[2];
    const float* b1 = (const float*)d_in[3];
    const float* W2 = (const float*)d_in[4];
    const float* b2 = (const float*)d_in[5];
    const float* W3 = (const float*)d_in[6];
    const float* b3 = (const float*)d_in[7];
    float* outp = (float*)d_out;

    int n = in_sizes[0] / F_IN;   // 100000
    int E = in_sizes[1] / 2;      // 1600000

    char* p = (char*)d_ws;
    auto alloc = [&](size_t bytes) -> char* {
        char* r = p;
        p += (bytes + 511) & ~(size_t)511;
        return r;
    };
    int*            flag   = (int*)alloc(4);
    int*            deg    = (int*)alloc((size_t)n * 4);
    float*          dinv   = (float*)alloc((size_t)n * 4);
    int*            rp     = (int*)alloc((size_t)(n + 1) * 4);
    int*            bsum   = (int*)alloc(4096);
    int*            rank   = (int*)alloc((size_t)E * 4);
    int*            csr    = (int*)alloc((size_t)E * 4);
    unsigned short* W1s    = (unsigned short*)alloc((size_t)F_IN * H1P * 2);
    unsigned short* W2s    = (unsigned short*)alloc((size_t)H1P * H2P * 2);
    unsigned short* W3s    = (unsigned short*)alloc((size_t)H2P * NCP * 2);
    float*          b1p    = (float*)alloc(H1P * 4);
    float*          b2p    = (float*)alloc(H2P * 4);
    float*          b3p    = (float*)alloc(NCP * 4);
    unsigned short* h1     = (unsigned short*)alloc((size_t)n * H1P * 2);
    unsigned short* h1agg  = (unsigned short*)alloc((size_t)n * H1P * 2);
    unsigned short* h2     = (unsigned short*)alloc((size_t)n * H2P * 2);
    unsigned short* h2agg  = (unsigned short*)alloc((size_t)n * H2P * 2);

    hipMemsetAsync(flag, 1, 4, stream);
    hipMemsetAsync(deg, 0, (size_t)n * 4, stream);

    k_detect<<<16, 256, 0, stream>>>(ei, flag);

    int eb = (E + 255) / 256;
    k_hist<<<eb, 256, 0, stream>>>(ei, E, flag, deg, rank);
    k_dinv<<<(n + 255) / 256, 256, 0, stream>>>(deg, dinv, n);

    int nb = (n + 1023) / 1024;
    k_scan1<<<nb, 256, 0, stream>>>(deg, rp, bsum, n);
    k_scan2<<<1, 128, 0, stream>>>(bsum, nb);
    k_scan3<<<(n + 1 + 255) / 256, 256, 0, stream>>>(bsum, rp, n, E);

    int bw = (n + 7) / 8;
    int nch = 256;
    int chunk = (E + nch - 1) / nch;
    k_fill<<<nch * 8, 256, 0, stream>>>(ei, E, flag, rp, rank, csr, bw, chunk);

    k_prepw<<<(F_IN * H1P + 255) / 256, 256, 0, stream>>>(W1, W1s, F_IN, H1V, F_IN, H1P);
    k_prepw<<<(H1P * H2P + 255) / 256, 256, 0, stream>>>(W2, W2s, H1V, H2V, H1P, H2P);
    k_prepw<<<(H2P * NCP + 255) / 256, 256, 0, stream>>>(W3, W3s, H2V, NC, H2P, NCP);
    k_pad<<<1, 256, 0, stream>>>(b1, b1p, 1, H1V, H1P, H1P);
    k_pad<<<1, 256, 0, stream>>>(b2, b2p, 1, H2V, H2P, H2P);
    k_padneg<<<1, 64, 0, stream>>>(b3, b3p, NC, NCP);

    int gb = (n + 127) / 128;
    // layer 1
    k_gemm1<<<gb, 512, 0, stream>>>(x, (const short8*)W1s, dinv, h1, n);
    k_gat<H1P / 4, 1><<<(n + 3) / 4, 256, 0, stream>>>((const uint2*)h1, dinv, rp, csr, b1p, h1agg, n);
    // layer 2
    k_gemm2<<<gb, 512, 0, stream>>>(h1agg, (const short8*)W2s, dinv, h2, n);
    k_gat2<<<(n + 7) / 8, 256, 0, stream>>>((const uint2*)h2, dinv, rp, csr, b2p, (uint2*)h2agg, n);
    // output layer + log_softmax (MFMA, fused)
    k_out<<<(n + 63) / 64, 256, 0, stream>>>(h2agg, (const short8*)W3s, b3p, outp, n);
}